// Round 2
// baseline (1827.328 us; speedup 1.0000x reference)
//
#include <hip/hip_runtime.h>
#include <hip/hip_bf16.h>

// Problem constants
#define NN 8
#define CC 128
#define HH 128
#define WW 128
#define HWP (HH*WW)
#define KK 7
#define DD 49            // K*K
#define NPH 31           // full unfold patch grid (data side)
#define NPATCH 961       // 31*31
#define PHN 19           // only output patches ph,pw in [0,19) survive recon crop
#define ROWS_PER_N (CC*NPATCH)   // 123008 rows of the (c,patch) row space per image

// ---------------------------------------------------------------------------
// Fused per-patch attention kernel.
//
// CRITICAL reference quirk: ex_p.reshape(N*npatch, C, D) reinterprets the
// (N, C, nph, npw, K, K)-ordered buffer. Pseudo-batch b's "channel" c2 is
// row r = b*128 + c2 of the (n, c_u, p_u)-ordered row space:
//     c_u = (r mod 123008) / 961,  p_u = r mod 961   (n_u == n always, since
//     b*128 = n*123008 + p'*128 and p'*128 + c2 < 123008).
// recon()'s reshape IS consistent with b=(n,ph,pw), channel=c2 on the output
// side, so only this gather is scrambled; fold/residual/gates use true (c2,h,w).
//
// Per block (n, ph<19, pw<19):
//   ec = Wce @ ex_s                    (128x49)   ex_s = scrambled gather
//   A[d,e] = sum_o ec[o,d] q_s[o,e]    (49x49)
//   P1 = softmax_d(A), P2 = softmax_e(A)
//   me[d] = sigmoid( sum_e (g1^T q_s)[e] * P2[d,e] )     (linear gate trick)
//   mq[e] = sigmoid( sum_d (g2^T ex_s)[d] * P1[d,e] )
//   xe[c,d] = (sum_e q_s[c,e] P2[d,e]) * me[d] + exemplar[n,c,pix(d)]
//   xq[c,e] = (sum_d ex_s[c,d] P1[d,e]) * mq[e] + query[n,c,pix(e)]
// folded straight into NCHW at rows ph*7+kh (cropped at 128).
// ---------------------------------------------------------------------------
__global__ __launch_bounds__(512, 1) void attn_kernel(
    const float* __restrict__ ex_g, const float* __restrict__ q_g,
    const float* __restrict__ Wce, const float* __restrict__ wg1,
    const float* __restrict__ wg2,
    float* __restrict__ xe, float* __restrict__ xq)
{
    __shared__ float s_ex[CC*DD];          // 24.5 KB (scrambled-gather rows)
    __shared__ float s_q [CC*DD];          // 24.5 KB
    __shared__ float s_ec[CC*DD];          // 24.5 KB, reused for P1+P2 (2*2401)
    __shared__ float s_A [DD*DD];          // 9.6 KB
    __shared__ float s_m1[DD], s_l1[DD], s_m2[DD], s_l2[DD];
    __shared__ float s_g1[DD], s_g2[DD], s_me[DD], s_mq[DD];

    const int t  = threadIdx.x;
    const int n  = blockIdx.y;
    const int ph = blockIdx.x / PHN;
    const int pw = blockIdx.x % PHN;
    const int pp = (ph * NPH + pw) * CC;   // p' * 128, base row offset within image

    const float* exn = ex_g + (size_t)n * CC * HWP;
    const float* qn  = q_g  + (size_t)n * CC * HWP;

    // ---- scrambled unfold gather ----
    for (int i = t; i < CC*DD; i += 512) {
        int c2 = i / DD, d = i - c2*DD;
        int kh = d / KK, kw = d - kh*KK;
        int rem  = pp + c2;                 // row within image's (c_u, p_u) space
        int c_u  = rem / NPATCH;
        int p_u  = rem - c_u * NPATCH;
        int ph_u = p_u / NPH;
        int pw_u = p_u - ph_u * NPH;
        int gi = (c_u*HH + ph_u*4 + kh)*WW + pw_u*4 + kw;
        s_ex[i] = exn[gi];
        s_q [i] = qn [gi];
    }
    __syncthreads();

    // ---- ec = Wce(128x128) @ ex_s(128x49) ----
    for (int i = t; i < CC*DD; i += 512) {
        int o = i / DD, d = i - o*DD;
        const float* wr = Wce + o*CC;
        float acc = 0.f;
        #pragma unroll 8
        for (int c = 0; c < CC; ++c) acc = fmaf(wr[c], s_ex[c*DD + d], acc);
        s_ec[i] = acc;
    }
    __syncthreads();

    // ---- A[d,e] = sum_o ec[o,d]*q_s[o,e]  (49x49) ----
    for (int i = t; i < DD*DD; i += 512) {
        int d = i / DD, e = i - d*DD;
        float acc = 0.f;
        #pragma unroll 8
        for (int o = 0; o < CC; ++o) acc = fmaf(s_ec[o*DD + d], s_q[o*DD + e], acc);
        s_A[i] = acc;
    }
    // gate projections (need only q_s/ex_s; run on other threads)
    if (t < DD) {                       // g1[e] = sum_c wg1[c]*q_s[c,e]
        float acc = 0.f;
        for (int c = 0; c < CC; ++c) acc = fmaf(wg1[c], s_q[c*DD + t], acc);
        s_g1[t] = acc;
    } else if (t >= 64 && t < 64 + DD) { // g2[d] = sum_c wg2[c]*ex_s[c,d]
        int d = t - 64;
        float acc = 0.f;
        for (int c = 0; c < CC; ++c) acc = fmaf(wg2[c], s_ex[c*DD + d], acc);
        s_g2[d] = acc;
    }
    __syncthreads();

    // ---- softmax stats: A1 over axis d (cols), B2 over axis e (rows) ----
    if (t < DD) {                        // column e = t
        float m = -1e30f;
        for (int d = 0; d < DD; ++d) m = fmaxf(m, s_A[d*DD + t]);
        float l = 0.f;
        for (int d = 0; d < DD; ++d) l += __expf(s_A[d*DD + t] - m);
        s_m1[t] = m; s_l1[t] = 1.f / l;
    } else if (t >= 64 && t < 64 + DD) { // row d = t-64
        int d = t - 64;
        float m = -1e30f;
        for (int e = 0; e < DD; ++e) m = fmaxf(m, s_A[d*DD + e]);
        float l = 0.f;
        for (int e = 0; e < DD; ++e) l += __expf(s_A[d*DD + e] - m);
        s_m2[d] = m; s_l2[d] = 1.f / l;
    }
    __syncthreads();

    float* P1 = s_ec;            // ec is dead now
    float* P2 = s_ec + DD*DD;
    for (int i = t; i < DD*DD; i += 512) {
        int d = i / DD, e = i - d*DD;
        float a = s_A[i];
        P1[i] = __expf(a - s_m1[e]) * s_l1[e];
        P2[i] = __expf(a - s_m2[d]) * s_l2[d];
    }
    __syncthreads();

    // ---- gate masks via linear trick ----
    if (t < DD) {
        int d = t;
        float a1 = 0.f, a2 = 0.f;
        for (int e = 0; e < DD; ++e)  a1 = fmaf(s_g1[e],  P2[d*DD + e], a1);
        s_me[d] = 1.f / (1.f + __expf(-a1));
        for (int dd = 0; dd < DD; ++dd) a2 = fmaf(s_g2[dd], P1[dd*DD + t], a2);
        s_mq[t] = 1.f / (1.f + __expf(-a2));
    }
    __syncthreads();

    // ---- attention outputs + gate + residual, folded straight to NCHW ----
    for (int i = t; i < CC*DD; i += 512) {
        int c = i / DD, d = i - c*DD;
        int kh = d / KK, kw = d - kh*KK;
        int h = ph*KK + kh, w = pw*KK + kw;
        if (h < HH && w < WW) {
            float ea = 0.f, qa = 0.f;
            #pragma unroll 7
            for (int e = 0; e < DD; ++e)  ea = fmaf(s_q [c*DD + e],  P2[d*DD + e], ea);
            #pragma unroll 7
            for (int dd = 0; dd < DD; ++dd) qa = fmaf(s_ex[c*DD + dd], P1[dd*DD + d], qa);
            int li = (c*HH + h)*WW + w;
            size_t gi = (size_t)n * CC * HWP + li;
            xe[gi] = ea * s_me[d] + exn[li];
            xq[gi] = qa * s_mq[d] + qn[li];
        }
    }
}

// ---------------------------------------------------------------------------
// Depthwise 3x3 (pad 1) + BN + ReLU. 4 pixels per thread along w (float4).
// Output channel placed at (coff + c) of CoutTot (writes concat layout direct).
// ---------------------------------------------------------------------------
__global__ __launch_bounds__(256) void dw_kernel(
    const float* __restrict__ x, float* __restrict__ y,
    const float* __restrict__ wdw, const float* __restrict__ g,
    const float* __restrict__ b, int CoutTot, int coff)
{
    int idx = blockIdx.x * 256 + threadIdx.x;     // N*128*H*(W/4) = 4,194,304
    int w4 = (idx & 31) * 4;
    int h  = (idx >> 5) & 127;
    int nc = idx >> 12;
    int c  = nc & 127;
    int n  = nc >> 7;

    const float* wp = wdw + (coff + c) * 9;
    const float* base = x + (size_t)nc * HWP;

    float acc0 = 0.f, acc1 = 0.f, acc2 = 0.f, acc3 = 0.f;
    #pragma unroll
    for (int j = 0; j < 3; ++j) {
        int hh = h - 1 + j;
        float e0, e1, e2, e3, e4, e5;
        if (hh >= 0 && hh < HH) {
            const float* row = base + hh * WW + w4;
            float4 v = *(const float4*)row;
            e1 = v.x; e2 = v.y; e3 = v.z; e4 = v.w;
            e0 = (w4 > 0)   ? row[-1] : 0.f;
            e5 = (w4 < 124) ? row[4]  : 0.f;
        } else { e0 = e1 = e2 = e3 = e4 = e5 = 0.f; }
        float wa = wp[j*3+0], wb = wp[j*3+1], wc = wp[j*3+2];
        acc0 += wa*e0 + wb*e1 + wc*e2;
        acc1 += wa*e1 + wb*e2 + wc*e3;
        acc2 += wa*e2 + wb*e3 + wc*e4;
        acc3 += wa*e3 + wb*e4 + wc*e5;
    }
    const float rs = 0.99999500003749968f;   // 1/sqrt(1+1e-5)
    float sc = g[coff + c] * rs, bi = b[coff + c];
    float4 o;
    o.x = fmaxf(acc0 * sc + bi, 0.f);
    o.y = fmaxf(acc1 * sc + bi, 0.f);
    o.z = fmaxf(acc2 * sc + bi, 0.f);
    o.w = fmaxf(acc3 * sc + bi, 0.f);
    float* outp = y + (((size_t)n * CoutTot + coff + c) * HH + h) * WW + w4;
    *(float4*)outp = o;
}

// ---------------------------------------------------------------------------
// Pointwise 1x1 (Cin -> 128) + BN + ReLU as a tiled GEMM.
// Block: (n, 64-pixel tile). Stage z[Cin][64] in LDS; thread = 1 out-ch x 32 px.
// Results staged back through LDS (stride 65) for coalesced stores.
// ---------------------------------------------------------------------------
__global__ __launch_bounds__(256) void pw_kernel(
    const float* __restrict__ z, float* __restrict__ out,
    const float* __restrict__ Wp, const float* __restrict__ g,
    const float* __restrict__ b, int Cin)
{
    __shared__ float s_z[256 * 64];   // 64 KB (max Cin=256)
    const int t  = threadIdx.x;
    const int n  = blockIdx.y;
    const int p0 = blockIdx.x * 64;

    const float* zn = z + (size_t)n * Cin * HWP;
    for (int i = t; i < Cin * 64; i += 256) {
        int c = i >> 6, p = i & 63;
        s_z[i] = zn[c * HWP + p0 + p];
    }
    __syncthreads();

    const int o   = t >> 1;
    const int phh = (t & 1) * 32;
    float acc[32];
    #pragma unroll
    for (int k = 0; k < 32; ++k) acc[k] = 0.f;

    const float* wr = Wp + o * Cin;
    for (int c = 0; c < Cin; ++c) {
        float wv = wr[c];
        const float4* zp4 = (const float4*)(s_z + c * 64 + phh); // broadcast reads
        #pragma unroll
        for (int k4 = 0; k4 < 8; ++k4) {
            float4 v = zp4[k4];
            acc[k4*4+0] = fmaf(wv, v.x, acc[k4*4+0]);
            acc[k4*4+1] = fmaf(wv, v.y, acc[k4*4+1]);
            acc[k4*4+2] = fmaf(wv, v.z, acc[k4*4+2]);
            acc[k4*4+3] = fmaf(wv, v.w, acc[k4*4+3]);
        }
    }
    const float rs = 0.99999500003749968f;
    float sc = g[o] * rs, bi = b[o];
    __syncthreads();
    #pragma unroll
    for (int k = 0; k < 32; ++k)
        s_z[o * 65 + phh + k] = fmaxf(acc[k] * sc + bi, 0.f);
    __syncthreads();

    float* on = out + (size_t)n * 128 * HWP;
    for (int i = t; i < 128 * 64; i += 256) {
        int oo = i >> 6, p = i & 63;
        on[oo * HWP + p0 + p] = s_z[oo * 65 + p];
    }
}

// ---------------------------------------------------------------------------
extern "C" void kernel_launch(void* const* d_in, const int* in_sizes, int n_in,
                              void* d_out, int out_size, void* d_ws, size_t ws_size,
                              hipStream_t stream) {
    const float* exemplar = (const float*)d_in[0];
    const float* query    = (const float*)d_in[1];
    const float* w_conv_e = (const float*)d_in[2];
    const float* w_gate1  = (const float*)d_in[3];
    const float* w_gate2  = (const float*)d_in[4];
    const float* dw1_w    = (const float*)d_in[5];
    const float* bn1a_g   = (const float*)d_in[6];
    const float* bn1a_b   = (const float*)d_in[7];
    const float* pw1_w    = (const float*)d_in[8];
    const float* bn1b_g   = (const float*)d_in[9];
    const float* bn1b_b   = (const float*)d_in[10];
    const float* dwf_w    = (const float*)d_in[11];
    const float* bnfa_g   = (const float*)d_in[12];
    const float* bnfa_b   = (const float*)d_in[13];
    const float* pwf_w    = (const float*)d_in[14];
    const float* bnfb_g   = (const float*)d_in[15];
    const float* bnfb_b   = (const float*)d_in[16];

    float* out = (float*)d_out;
    float* ws  = (float*)d_ws;
    const size_t SZ = (size_t)NN * CC * HWP;     // 16,777,216 floats = 67.1 MB
    float* bufA = ws;              // x_e -> e_out
    float* bufB = ws + SZ;         // x_q -> q_out
    float* bufC = ws + 2 * SZ;     // z_e; later T (spans 2*SZ as (N,256,H,W))
    float* bufD = ws + 3 * SZ;     // z_q
    float* T    = bufC;

    // 1) fused attention + gating + residual
    attn_kernel<<<dim3(PHN * PHN, NN), 512, 0, stream>>>(
        exemplar, query, w_conv_e, w_gate1, w_gate2, bufA, bufB);

    // 2) dsconv #1 depthwise (shared weights for both streams)
    dw_kernel<<<16384, 256, 0, stream>>>(bufA, bufC, dw1_w, bn1a_g, bn1a_b, 128, 0);
    dw_kernel<<<16384, 256, 0, stream>>>(bufB, bufD, dw1_w, bn1a_g, bn1a_b, 128, 0);

    // 3) dsconv #1 pointwise
    pw_kernel<<<dim3(256, NN), 256, 0, stream>>>(bufC, bufA, pw1_w, bn1b_g, bn1b_b, 128);
    pw_kernel<<<dim3(256, NN), 256, 0, stream>>>(bufD, bufB, pw1_w, bn1b_g, bn1b_b, 128);

    // 4) final depthwise on concat (writes (N,256,H,W) layout directly)
    dw_kernel<<<16384, 256, 0, stream>>>(bufA, T, dwf_w, bnfa_g, bnfa_b, 256, 0);
    dw_kernel<<<16384, 256, 0, stream>>>(bufB, T, dwf_w, bnfa_g, bnfa_b, 256, 128);

    // 5) final pointwise 256 -> 128
    pw_kernel<<<dim3(256, NN), 256, 0, stream>>>(T, out, pwf_w, bnfb_g, bnfb_b, 256);
}

// Round 3
// 1278.871 us; speedup vs baseline: 1.4289x; 1.4289x over previous
//
#include <hip/hip_runtime.h>
#include <hip/hip_bf16.h>

// Problem constants
#define NN 8
#define CC 128
#define HH 128
#define WW 128
#define HWP (HH*WW)
#define KK 7
#define DD 49            // K*K
#define NPH 31           // full unfold patch grid (data side)
#define NPATCH 961       // 31*31
#define PHN 19           // only output patches ph,pw in [0,19) survive recon crop
#define PAD 52           // padded leading dim for 49-wide LDS tiles (f4-aligned)

// ---------------------------------------------------------------------------
// Fused per-patch attention kernel, register-tiled.
// Scrambled-gather semantics identical to the R2-passing version (reference's
// reshape reinterprets (N,C,nph,npw,K,K) memory order; only the gather is
// scrambled, fold/residual/gates use true (c,h,w)).
// ---------------------------------------------------------------------------
__global__ __launch_bounds__(512, 1) void attn_kernel(
    const float* __restrict__ ex_g, const float* __restrict__ q_g,
    const float* __restrict__ Wce, const float* __restrict__ wg1,
    const float* __restrict__ wg2,
    float* __restrict__ xe, float* __restrict__ xq)
{
    __shared__ float s_ex[CC*PAD];        // 26.6 KB  [c][d] pad 52
    __shared__ float s_q [CC*PAD];        // 26.6 KB  [c][e] pad 52
    __shared__ float s_ec[CC*PAD];        // 26.6 KB  [o][d] pad 52
    __shared__ float s_A [PAD*PAD];       // 10.8 KB  [d][e] pad 52 (rows 49..51 = 0)
    __shared__ float s_P1[PAD*PAD];       // 10.8 KB
    __shared__ float s_P2[PAD*PAD];       // 10.8 KB
    __shared__ float s_W [32*130];        // 16.6 KB  weight chunk [cc][o] pad 130
    __shared__ float s_m1[PAD], s_l1[PAD], s_m2[PAD], s_l2[PAD];
    __shared__ float s_g1[PAD], s_g2[PAD], s_me[PAD], s_mq[PAD];

    const int t  = threadIdx.x;
    const int n  = blockIdx.y;
    const int ph = blockIdx.x / PHN;
    const int pw = blockIdx.x % PHN;
    const int pp = (ph * NPH + pw) * CC;   // p' * 128, base row offset in image

    const float* exn = ex_g + (size_t)n * CC * HWP;
    const float* qn  = q_g  + (size_t)n * CC * HWP;

    // ---- scrambled unfold gather (identical index math to passing R2) ----
    for (int i = t; i < CC*DD; i += 512) {
        int c2 = i / DD, d = i - c2*DD;
        int kh = d / KK, kw = d - kh*KK;
        int rem  = pp + c2;
        int c_u  = rem / NPATCH;
        int p_u  = rem - c_u * NPATCH;
        int ph_u = p_u / NPH;
        int pw_u = p_u - ph_u * NPH;
        int gi = (c_u*HH + ph_u*4 + kh)*WW + pw_u*4 + kw;
        s_ex[c2*PAD + d] = exn[gi];
        s_q [c2*PAD + d] = qn [gi];
    }
    // zero pad columns (d=49..51) so GEMM pads propagate zeros
    if (t < CC*3) {
        int c = t / 3, j = t - (t/3)*3;
        s_ex[c*PAD + DD + j] = 0.f;
        s_q [c*PAD + DD + j] = 0.f;
    }
    if (t < PAD) { s_m1[t]=0.f; s_l1[t]=0.f; s_m2[t]=0.f; s_l2[t]=0.f;
                   s_g1[t]=0.f; s_g2[t]=0.f; }

    // ---- ec = Wce(128x128) @ ex_s(128x49), 4x4 register tiles ----
    // tile grid: 32 o-groups x 13 d-groups = 416 active threads
    const int eg_o = t / 13, eg_d = t - (t/13)*13;
    const int o0 = eg_o*4, d0 = eg_d*4;
    float ac[4][4];
    #pragma unroll
    for (int i = 0; i < 4; ++i)
        #pragma unroll
        for (int j = 0; j < 4; ++j) ac[i][j] = 0.f;

    for (int kb = 0; kb < 4; ++kb) {
        // stage W chunk: W[o][kb*32+cc] -> s_W[cc*130+o]  (2-way banks = free)
        for (int i = t; i < 128*32; i += 512) {
            int o = i >> 5, cc = i & 31;
            s_W[cc*130 + o] = Wce[o*CC + kb*32 + cc];
        }
        __syncthreads();
        if (t < 416) {
            #pragma unroll 4
            for (int cc = 0; cc < 32; ++cc) {
                float4 wv = *(const float4*)&s_W[cc*130 + o0];
                float4 xv = *(const float4*)&s_ex[(kb*32+cc)*PAD + d0];
                float wr[4] = {wv.x, wv.y, wv.z, wv.w};
                float xr[4] = {xv.x, xv.y, xv.z, xv.w};
                #pragma unroll
                for (int i = 0; i < 4; ++i)
                    #pragma unroll
                    for (int j = 0; j < 4; ++j)
                        ac[i][j] = fmaf(wr[i], xr[j], ac[i][j]);
            }
        }
        __syncthreads();
    }
    if (t < 416) {
        #pragma unroll
        for (int i = 0; i < 4; ++i) {
            float4 v = make_float4(ac[i][0], ac[i][1], ac[i][2], ac[i][3]);
            *(float4*)&s_ec[(o0+i)*PAD + d0] = v;
        }
    }
    __syncthreads();

    // ---- gate projections ----
    if (t < DD) {                        // g1[e] = sum_c wg1[c]*q_s[c,e]
        float acc = 0.f;
        for (int c = 0; c < CC; ++c) acc = fmaf(wg1[c], s_q[c*PAD + t], acc);
        s_g1[t] = acc;
    } else if (t >= 64 && t < 64 + DD) { // g2[d] = sum_c wg2[c]*ex_s[c,d]
        int d = t - 64;
        float acc = 0.f;
        for (int c = 0; c < CC; ++c) acc = fmaf(wg2[c], s_ex[c*PAD + d], acc);
        s_g2[d] = acc;
    }
    __syncthreads();

    // ---- A[d,e] = sum_o ec[o,d]*q[o,e], 4x4 tiles, f4 operand rows ----
    if (t < 169) {
        int dg = t / 13, eg = t - (t/13)*13;
        int ad0 = dg*4, ae0 = eg*4;
        float aa[4][4];
        #pragma unroll
        for (int i = 0; i < 4; ++i)
            #pragma unroll
            for (int j = 0; j < 4; ++j) aa[i][j] = 0.f;
        #pragma unroll 4
        for (int k = 0; k < CC; ++k) {
            float4 ev = *(const float4*)&s_ec[k*PAD + ad0];
            float4 qv = *(const float4*)&s_q [k*PAD + ae0];
            float er[4] = {ev.x, ev.y, ev.z, ev.w};
            float qr[4] = {qv.x, qv.y, qv.z, qv.w};
            #pragma unroll
            for (int i = 0; i < 4; ++i)
                #pragma unroll
                for (int j = 0; j < 4; ++j)
                    aa[i][j] = fmaf(er[i], qr[j], aa[i][j]);
        }
        #pragma unroll
        for (int i = 0; i < 4; ++i) {
            float4 v = make_float4(aa[i][0], aa[i][1], aa[i][2], aa[i][3]);
            *(float4*)&s_A[(ad0+i)*PAD + ae0] = v;   // pad rows/cols are 0 by construction
        }
    }
    __syncthreads();

    // ---- softmax stats (valid region only) ----
    if (t < DD) {                        // column e = t, over d
        float m = -1e30f;
        for (int d = 0; d < DD; ++d) m = fmaxf(m, s_A[d*PAD + t]);
        float l = 0.f;
        for (int d = 0; d < DD; ++d) l += __expf(s_A[d*PAD + t] - m);
        s_m1[t] = m; s_l1[t] = 1.f / l;
    } else if (t >= 64 && t < 64 + DD) { // row d = t-64, over e
        int d = t - 64;
        float m = -1e30f;
        for (int e = 0; e < DD; ++e) m = fmaxf(m, s_A[d*PAD + e]);
        float l = 0.f;
        for (int e = 0; e < DD; ++e) l += __expf(s_A[d*PAD + e] - m);
        s_m2[d] = m; s_l2[d] = 1.f / l;
    }
    __syncthreads();

    // ---- P build over full padded area (pads give exact 0: A=0,m=0,linv=0) ----
    for (int i = t; i < PAD*PAD; i += 512) {
        int d = i / PAD, e = i - d*PAD;
        float a = s_A[i];
        s_P1[i] = __expf(a - s_m1[e]) * s_l1[e];
        s_P2[i] = __expf(a - s_m2[d]) * s_l2[d];
    }
    __syncthreads();

    // ---- gate masks ----
    if (t < DD) {
        float a1 = 0.f, a2 = 0.f;
        for (int e = 0; e < DD; ++e)  a1 = fmaf(s_g1[e],  s_P2[t*PAD + e], a1);
        s_me[t] = 1.f / (1.f + __expf(-a1));
        for (int dd = 0; dd < DD; ++dd) a2 = fmaf(s_g2[dd], s_P1[dd*PAD + t], a2);
        s_mq[t] = 1.f / (1.f + __expf(-a2));
    } else if (t >= DD && t < PAD) { s_me[t] = 0.f; s_mq[t] = 0.f; }
    __syncthreads();

    // ---- output GEMMs (xe and xq fused), 4x4 tiles over (c, X) ----
    // xe[c,X] = sum_k q[c,k]*P2[X,k];  xq[c,X] = sum_k ex[c,k]*P1[k,X]
    if (t < 416) {
        int cg = t / 13, xg = t - (t/13)*13;
        int c0 = cg*4, x0 = xg*4;
        float ae[4][4], aq[4][4];
        #pragma unroll
        for (int i = 0; i < 4; ++i)
            #pragma unroll
            for (int j = 0; j < 4; ++j) { ae[i][j] = 0.f; aq[i][j] = 0.f; }
        for (int k = 0; k < DD; ++k) {
            float4 p1 = *(const float4*)&s_P1[k*PAD + x0];
            float p1r[4] = {p1.x, p1.y, p1.z, p1.w};
            float qv[4], xv[4], p2[4];
            #pragma unroll
            for (int i = 0; i < 4; ++i) { qv[i] = s_q [(c0+i)*PAD + k];
                                          xv[i] = s_ex[(c0+i)*PAD + k]; }
            #pragma unroll
            for (int j = 0; j < 4; ++j)   p2[j] = s_P2[(x0+j)*PAD + k];
            #pragma unroll
            for (int i = 0; i < 4; ++i)
                #pragma unroll
                for (int j = 0; j < 4; ++j) {
                    ae[i][j] = fmaf(qv[i], p2[j],  ae[i][j]);
                    aq[i][j] = fmaf(xv[i], p1r[j], aq[i][j]);
                }
        }
        // epilogue: gate + residual, fold to NCHW
        size_t nbase = (size_t)n * CC * HWP;
        #pragma unroll
        for (int j = 0; j < 4; ++j) {
            int X = x0 + j;
            if (X < DD) {
                int kh = X / KK, kw = X - kh*KK;
                int h = ph*KK + kh, w = pw*KK + kw;
                if (h < HH && w < WW) {
                    float me = s_me[X], mq = s_mq[X];
                    #pragma unroll
                    for (int i = 0; i < 4; ++i) {
                        int li = ((c0+i)*HH + h)*WW + w;
                        xe[nbase + li] = ae[i][j] * me + exn[li];
                        xq[nbase + li] = aq[i][j] * mq + qn[li];
                    }
                }
            }
        }
    }
}

// ---------------------------------------------------------------------------
// Depthwise 3x3 (pad 1) + BN + ReLU. 4 rows x 4 cols per thread (register
// reuse of shared input rows: 9B/px read vs 18B/px single-row version).
// ---------------------------------------------------------------------------
__global__ __launch_bounds__(256) void dw_kernel(
    const float* __restrict__ x, float* __restrict__ y,
    const float* __restrict__ wdw, const float* __restrict__ g,
    const float* __restrict__ b, int CoutTot, int coff)
{
    int idx = blockIdx.x * 256 + threadIdx.x;   // NN*CC*32*32 = 1,048,576
    int w4 = (idx & 31) * 4;
    int h4 = ((idx >> 5) & 31) * 4;
    int nc = idx >> 10;
    int c  = nc & 127;
    int n  = nc >> 7;

    const float* wp = wdw + (coff + c) * 9;
    float wr[9];
    #pragma unroll
    for (int i = 0; i < 9; ++i) wr[i] = wp[i];

    const float* base = x + (size_t)nc * HWP;
    float acc[4][4];
    #pragma unroll
    for (int i = 0; i < 4; ++i)
        #pragma unroll
        for (int j = 0; j < 4; ++j) acc[i][j] = 0.f;

    #pragma unroll
    for (int r = 0; r < 6; ++r) {
        int hh = h4 - 1 + r;
        if (hh >= 0 && hh < HH) {
            const float* row = base + hh * WW + w4;
            float4 v = *(const float4*)row;
            float e[6];
            e[0] = (w4 > 0)   ? row[-1] : 0.f;
            e[1] = v.x; e[2] = v.y; e[3] = v.z; e[4] = v.w;
            e[5] = (w4 < 124) ? row[4]  : 0.f;
            int ilo = r - 2 > 0 ? r - 2 : 0;
            int ihi = r < 3 ? r : 3;
            for (int i = ilo; i <= ihi; ++i) {
                int j = r - i;                 // tap row 0..2
                float wa = wr[j*3], wb = wr[j*3+1], wc = wr[j*3+2];
                acc[i][0] += wa*e[0] + wb*e[1] + wc*e[2];
                acc[i][1] += wa*e[1] + wb*e[2] + wc*e[3];
                acc[i][2] += wa*e[2] + wb*e[3] + wc*e[4];
                acc[i][3] += wa*e[3] + wb*e[4] + wc*e[5];
            }
        }
    }
    const float rs = 0.99999500003749968f;   // 1/sqrt(1+1e-5)
    float sc = g[coff + c] * rs, bi = b[coff + c];
    float* outp = y + (((size_t)n * CoutTot + coff + c) * HH + h4) * WW + w4;
    #pragma unroll
    for (int i = 0; i < 4; ++i) {
        float4 o;
        o.x = fmaxf(acc[i][0] * sc + bi, 0.f);
        o.y = fmaxf(acc[i][1] * sc + bi, 0.f);
        o.z = fmaxf(acc[i][2] * sc + bi, 0.f);
        o.w = fmaxf(acc[i][3] * sc + bi, 0.f);
        *(float4*)(outp + i * WW) = o;
    }
}

// ---------------------------------------------------------------------------
// Pointwise 1x1 (Cin -> 128) + BN + ReLU, GEMM-tiled.
// Block: 128 out-ch x 128 px; thread: 8x8; k staged in 32-channel LDS chunks.
// 33.5 KB LDS -> 4 blocks/CU.
// ---------------------------------------------------------------------------
__global__ __launch_bounds__(256, 4) void pw_kernel(
    const float* __restrict__ z, float* __restrict__ out,
    const float* __restrict__ Wp, const float* __restrict__ g,
    const float* __restrict__ b, int Cin)
{
    __shared__ float s_w[32*130];   // [cc][o]  pad 130
    __shared__ float s_a[32*132];   // [cc][px] pad 132
    const int t  = threadIdx.x;
    const int n  = blockIdx.y;
    const int p0 = blockIdx.x * 128;
    const int o0  = (t >> 4) * 8;
    const int px0 = (t & 15) * 8;

    float acc[8][8];
    #pragma unroll
    for (int i = 0; i < 8; ++i)
        #pragma unroll
        for (int j = 0; j < 8; ++j) acc[i][j] = 0.f;

    const float* zn = z + (size_t)n * Cin * HWP;
    const int nch = Cin >> 5;
    for (int cb = 0; cb < nch; ++cb) {
        for (int i = t; i < 128*32; i += 256) {     // weights
            int o = i >> 5, cc = i & 31;
            s_w[cc*130 + o] = Wp[o*Cin + cb*32 + cc];
        }
        for (int i = t; i < 32*128; i += 256) {     // activations
            int cc = i >> 7, px = i & 127;
            s_a[cc*132 + px] = zn[(cb*32 + cc)*HWP + p0 + px];
        }
        __syncthreads();
        #pragma unroll 4
        for (int cc = 0; cc < 32; ++cc) {
            float4 w0 = *(const float4*)&s_w[cc*130 + o0];
            float4 w1 = *(const float4*)&s_w[cc*130 + o0 + 4];
            float4 a0 = *(const float4*)&s_a[cc*132 + px0];
            float4 a1 = *(const float4*)&s_a[cc*132 + px0 + 4];
            float wv[8] = {w0.x,w0.y,w0.z,w0.w, w1.x,w1.y,w1.z,w1.w};
            float av[8] = {a0.x,a0.y,a0.z,a0.w, a1.x,a1.y,a1.z,a1.w};
            #pragma unroll
            for (int i = 0; i < 8; ++i)
                #pragma unroll
                for (int j = 0; j < 8; ++j)
                    acc[i][j] = fmaf(wv[i], av[j], acc[i][j]);
        }
        __syncthreads();
    }
    const float rs = 0.99999500003749968f;
    float* on = out + (size_t)n * 128 * HWP;
    #pragma unroll
    for (int i = 0; i < 8; ++i) {
        int o = o0 + i;
        float sc = g[o] * rs, bi = b[o];
        float4 v0, v1;
        v0.x = fmaxf(acc[i][0]*sc + bi, 0.f);
        v0.y = fmaxf(acc[i][1]*sc + bi, 0.f);
        v0.z = fmaxf(acc[i][2]*sc + bi, 0.f);
        v0.w = fmaxf(acc[i][3]*sc + bi, 0.f);
        v1.x = fmaxf(acc[i][4]*sc + bi, 0.f);
        v1.y = fmaxf(acc[i][5]*sc + bi, 0.f);
        v1.z = fmaxf(acc[i][6]*sc + bi, 0.f);
        v1.w = fmaxf(acc[i][7]*sc + bi, 0.f);
        *(float4*)&on[o*HWP + p0 + px0]     = v0;
        *(float4*)&on[o*HWP + p0 + px0 + 4] = v1;
    }
}

// ---------------------------------------------------------------------------
extern "C" void kernel_launch(void* const* d_in, const int* in_sizes, int n_in,
                              void* d_out, int out_size, void* d_ws, size_t ws_size,
                              hipStream_t stream) {
    const float* exemplar = (const float*)d_in[0];
    const float* query    = (const float*)d_in[1];
    const float* w_conv_e = (const float*)d_in[2];
    const float* w_gate1  = (const float*)d_in[3];
    const float* w_gate2  = (const float*)d_in[4];
    const float* dw1_w    = (const float*)d_in[5];
    const float* bn1a_g   = (const float*)d_in[6];
    const float* bn1a_b   = (const float*)d_in[7];
    const float* pw1_w    = (const float*)d_in[8];
    const float* bn1b_g   = (const float*)d_in[9];
    const float* bn1b_b   = (const float*)d_in[10];
    const float* dwf_w    = (const float*)d_in[11];
    const float* bnfa_g   = (const float*)d_in[12];
    const float* bnfa_b   = (const float*)d_in[13];
    const float* pwf_w    = (const float*)d_in[14];
    const float* bnfb_g   = (const float*)d_in[15];
    const float* bnfb_b   = (const float*)d_in[16];

    float* out = (float*)d_out;
    float* ws  = (float*)d_ws;
    const size_t SZ = (size_t)NN * CC * HWP;     // 16,777,216 floats
    float* bufA = ws;              // x_e -> e_out
    float* bufB = ws + SZ;         // x_q -> q_out
    float* bufC = ws + 2 * SZ;     // z_e; later T (spans 2*SZ as (N,256,H,W))
    float* bufD = ws + 3 * SZ;     // z_q
    float* T    = bufC;

    // 1) fused attention + gating + residual
    attn_kernel<<<dim3(PHN * PHN, NN), 512, 0, stream>>>(
        exemplar, query, w_conv_e, w_gate1, w_gate2, bufA, bufB);

    // 2) dsconv #1 depthwise
    dw_kernel<<<4096, 256, 0, stream>>>(bufA, bufC, dw1_w, bn1a_g, bn1a_b, 128, 0);
    dw_kernel<<<4096, 256, 0, stream>>>(bufB, bufD, dw1_w, bn1a_g, bn1a_b, 128, 0);

    // 3) dsconv #1 pointwise
    pw_kernel<<<dim3(128, NN), 256, 0, stream>>>(bufC, bufA, pw1_w, bn1b_g, bn1b_b, 128);
    pw_kernel<<<dim3(128, NN), 256, 0, stream>>>(bufD, bufB, pw1_w, bn1b_g, bn1b_b, 128);

    // 4) final depthwise on concat (writes (N,256,H,W) layout directly)
    dw_kernel<<<4096, 256, 0, stream>>>(bufA, T, dwf_w, bnfa_g, bnfa_b, 256, 0);
    dw_kernel<<<4096, 256, 0, stream>>>(bufB, T, dwf_w, bnfa_g, bnfa_b, 256, 128);

    // 5) final pointwise 256 -> 128
    pw_kernel<<<dim3(128, NN), 256, 0, stream>>>(T, out, pwf_w, bnfb_g, bnfb_b, 256);
}

// Round 4
// 943.012 us; speedup vs baseline: 1.9378x; 1.3562x over previous
//
#include <hip/hip_runtime.h>
#include <hip/hip_bf16.h>

// Problem constants
#define NN 8
#define CC 128
#define HH 128
#define WW 128
#define HWP (HH*WW)
#define KK 7
#define DD 49            // K*K
#define NPH 31           // full unfold patch grid (data side)
#define NPATCH 961       // 31*31
#define PHN 19           // only output patches ph,pw in [0,19) survive recon crop
#define PAD 52           // padded leading dim for 49-wide LDS tiles (f4-aligned)
#define PP2 (PAD*PAD)    // 2704

// ---------------------------------------------------------------------------
// Fused per-patch attention kernel, register-tiled, LDS-dieted to 81.5 KB so
// 2 blocks/CU co-reside (4 waves/SIMD). Scrambled-gather semantics identical
// to the R2/R3-passing versions.
//
// LDS overlay plan (s_scr, 128*PAD floats):
//   phase ec:   s_scr[o*PAD+d] = ec            (all 128 rows)
//   phase A:    A accumulated in REGISTERS while reading ec; after barrier,
//               A stored at s_scr[0..2704)     (ec dead)
//   phase P:    P1 at s_scr[2704..5408), P2 overwrites A in place
// Output GEMM accumulates in registers; results stored back into s_ex/s_q
// (gather inputs dead), then final loop writes d-major -> 7-float w-runs.
// ---------------------------------------------------------------------------
__global__ __launch_bounds__(512, 4) void attn_kernel(
    const float* __restrict__ ex_g, const float* __restrict__ q_g,
    const float* __restrict__ Wce, const float* __restrict__ wg1,
    const float* __restrict__ wg2,
    float* __restrict__ xe, float* __restrict__ xq)
{
    __shared__ float s_ex[CC*PAD];        // 26.6 KB  gather ex -> xe results
    __shared__ float s_q [CC*PAD];        // 26.6 KB  gather q  -> xq results
    __shared__ float s_scr[CC*PAD];       // 26.6 KB  ec -> A/P2 + P1
    __shared__ float s_m1[PAD], s_l1[PAD], s_m2[PAD], s_l2[PAD];
    __shared__ float s_g1[PAD], s_g2[PAD], s_me[PAD], s_mq[PAD];

    const int t  = threadIdx.x;
    const int n  = blockIdx.y;
    const int ph = blockIdx.x / PHN;
    const int pw = blockIdx.x % PHN;
    const int pp = (ph * NPH + pw) * CC;   // p' * 128, base row offset in image

    const float* exn = ex_g + (size_t)n * CC * HWP;
    const float* qn  = q_g  + (size_t)n * CC * HWP;

    // ---- scrambled unfold gather ----
    for (int i = t; i < CC*DD; i += 512) {
        int c2 = i / DD, d = i - c2*DD;
        int kh = d / KK, kw = d - kh*KK;
        int rem  = pp + c2;
        int c_u  = rem / NPATCH;
        int p_u  = rem - c_u * NPATCH;
        int ph_u = p_u / NPH;
        int pw_u = p_u - ph_u * NPH;
        int gi = (c_u*HH + ph_u*4 + kh)*WW + pw_u*4 + kw;
        s_ex[c2*PAD + d] = exn[gi];
        s_q [c2*PAD + d] = qn [gi];
    }
    if (t < CC*3) {    // zero pad cols d=49..51
        int c = t / 3, j = t - (t/3)*3;
        s_ex[c*PAD + DD + j] = 0.f;
        s_q [c*PAD + DD + j] = 0.f;
    }
    __syncthreads();

    // ---- ec = Wce(128x128) @ ex_s(128x49): 4x4 tiles, W f4 from global ----
    // tile grid: 32 o-groups x 13 d-groups = 416 active threads
    {
        const int eg_o = t / 13, eg_d = t - (t/13)*13;
        const int o0 = eg_o*4, d0 = eg_d*4;
        float ac[4][4];
        #pragma unroll
        for (int i = 0; i < 4; ++i)
            #pragma unroll
            for (int j = 0; j < 4; ++j) ac[i][j] = 0.f;
        if (t < 416) {
            for (int k = 0; k < CC; k += 4) {
                float xm[4][4];
                #pragma unroll
                for (int kk = 0; kk < 4; ++kk) {
                    float4 xv = *(const float4*)&s_ex[(k+kk)*PAD + d0];
                    xm[kk][0]=xv.x; xm[kk][1]=xv.y; xm[kk][2]=xv.z; xm[kk][3]=xv.w;
                }
                #pragma unroll
                for (int i = 0; i < 4; ++i) {
                    float4 wv = *(const float4*)&Wce[(o0+i)*CC + k];
                    float wr[4] = {wv.x, wv.y, wv.z, wv.w};
                    #pragma unroll
                    for (int kk = 0; kk < 4; ++kk)
                        #pragma unroll
                        for (int j = 0; j < 4; ++j)
                            ac[i][j] = fmaf(wr[kk], xm[kk][j], ac[i][j]);
                }
            }
        }
        __syncthreads();   // (nothing written yet; keeps gather reads done)
        if (t < 416) {
            #pragma unroll
            for (int i = 0; i < 4; ++i)
                *(float4*)&s_scr[(o0+i)*PAD + d0] =
                    make_float4(ac[i][0], ac[i][1], ac[i][2], ac[i][3]);
        }
    }
    __syncthreads();

    // ---- A[d,e] = sum_o ec[o,d]*q[o,e] in registers; gates in parallel ----
    float aa[4][4];
    int ad0 = 0, ae0 = 0;
    if (t < 169) {
        int dg = t / 13, eg = t - (t/13)*13;
        ad0 = dg*4; ae0 = eg*4;
        #pragma unroll
        for (int i = 0; i < 4; ++i)
            #pragma unroll
            for (int j = 0; j < 4; ++j) aa[i][j] = 0.f;
        #pragma unroll 4
        for (int k = 0; k < CC; ++k) {
            float4 ev = *(const float4*)&s_scr[k*PAD + ad0];
            float4 qv = *(const float4*)&s_q [k*PAD + ae0];
            float er[4] = {ev.x, ev.y, ev.z, ev.w};
            float qr[4] = {qv.x, qv.y, qv.z, qv.w};
            #pragma unroll
            for (int i = 0; i < 4; ++i)
                #pragma unroll
                for (int j = 0; j < 4; ++j)
                    aa[i][j] = fmaf(er[i], qr[j], aa[i][j]);
        }
    } else if (t >= 192 && t < 192 + DD) {   // g1[e] = sum_c wg1[c]*q[c,e]
        int e = t - 192;
        float acc = 0.f;
        for (int c = 0; c < CC; ++c) acc = fmaf(wg1[c], s_q[c*PAD + e], acc);
        s_g1[e] = acc;
    } else if (t >= 256 && t < 256 + DD) {   // g2[d] = sum_c wg2[c]*ex[c,d]
        int d = t - 256;
        float acc = 0.f;
        for (int c = 0; c < CC; ++c) acc = fmaf(wg2[c], s_ex[c*PAD + d], acc);
        s_g2[d] = acc;
    }
    __syncthreads();                      // ec reads complete
    if (t < 169) {                        // store A over dead ec rows 0..51
        #pragma unroll
        for (int i = 0; i < 4; ++i)
            *(float4*)&s_scr[(ad0+i)*PAD + ae0] =
                make_float4(aa[i][0], aa[i][1], aa[i][2], aa[i][3]);
    }
    __syncthreads();

    // ---- softmax stats over valid 49x49 region; pads -> exact 0 ----
    if (t < PAD) {                        // column e = t (A1: softmax over d)
        if (t < DD) {
            float m = -1e30f;
            for (int d = 0; d < DD; ++d) m = fmaxf(m, s_scr[d*PAD + t]);
            float l = 0.f;
            for (int d = 0; d < DD; ++d) l += __expf(s_scr[d*PAD + t] - m);
            s_m1[t] = m; s_l1[t] = 1.f / l;
        } else { s_m1[t] = 0.f; s_l1[t] = 0.f; }
    } else if (t >= 64 && t < 64 + PAD) { // row d (B2: softmax over e)
        int d = t - 64;
        if (d < DD) {
            float m = -1e30f;
            for (int e = 0; e < DD; ++e) m = fmaxf(m, s_scr[d*PAD + e]);
            float l = 0.f;
            for (int e = 0; e < DD; ++e) l += __expf(s_scr[d*PAD + e] - m);
            s_m2[d] = m; s_l2[d] = 1.f / l;
        } else { s_m2[d] = 0.f; s_l2[d] = 0.f; }
    }
    __syncthreads();

    // ---- P build: P1 to scr[2704..5408), P2 overwrites A in place ----
    float* P1 = s_scr + PP2;
    float* P2 = s_scr;
    for (int i = t; i < PP2; i += 512) {
        int d = i / PAD, e = i - d*PAD;
        float a = s_scr[i];
        P1[i] = __expf(a - s_m1[e]) * s_l1[e];   // pad cols/rows -> *0 = 0
        P2[i] = __expf(a - s_m2[d]) * s_l2[d];
    }
    __syncthreads();

    // ---- gate masks via linear trick ----
    if (t < PAD) {
        if (t < DD) {
            float a1 = 0.f, a2 = 0.f;
            for (int e = 0; e < DD; ++e)  a1 = fmaf(s_g1[e],  P2[t*PAD + e], a1);
            s_me[t] = 1.f / (1.f + __expf(-a1));
            for (int dd = 0; dd < DD; ++dd) a2 = fmaf(s_g2[dd], P1[dd*PAD + t], a2);
            s_mq[t] = 1.f / (1.f + __expf(-a2));
        } else { s_me[t] = 0.f; s_mq[t] = 0.f; }
    }
    __syncthreads();

    // ---- output GEMMs in registers: xe[c,X]=sum_k q[c,k]P2[X,k],
    //      xq[c,X]=sum_k ex[c,k]P1[k,X] ----
    float ae[4][4], aq[4][4];
    int c0 = 0, x0 = 0;
    if (t < 416) {
        int cg = t / 13, xg = t - (t/13)*13;
        c0 = cg*4; x0 = xg*4;
        #pragma unroll
        for (int i = 0; i < 4; ++i)
            #pragma unroll
            for (int j = 0; j < 4; ++j) { ae[i][j] = 0.f; aq[i][j] = 0.f; }
        for (int k = 0; k < DD; ++k) {
            float4 p1 = *(const float4*)&P1[k*PAD + x0];
            float p1r[4] = {p1.x, p1.y, p1.z, p1.w};
            float qv[4], xv[4], p2[4];
            #pragma unroll
            for (int i = 0; i < 4; ++i) { qv[i] = s_q [(c0+i)*PAD + k];
                                          xv[i] = s_ex[(c0+i)*PAD + k]; }
            #pragma unroll
            for (int j = 0; j < 4; ++j)   p2[j] = P2[(x0+j)*PAD + k];
            #pragma unroll
            for (int i = 0; i < 4; ++i)
                #pragma unroll
                for (int j = 0; j < 4; ++j) {
                    ae[i][j] = fmaf(qv[i], p2[j],  ae[i][j]);
                    aq[i][j] = fmaf(xv[i], p1r[j], aq[i][j]);
                }
        }
    }
    __syncthreads();                 // all reads of s_ex/s_q done
    if (t < 416) {                   // stash results over dead gather tiles
        #pragma unroll
        for (int i = 0; i < 4; ++i) {
            *(float4*)&s_ex[(c0+i)*PAD + x0] =
                make_float4(ae[i][0], ae[i][1], ae[i][2], ae[i][3]);
            *(float4*)&s_q [(c0+i)*PAD + x0] =
                make_float4(aq[i][0], aq[i][1], aq[i][2], aq[i][3]);
        }
    }
    __syncthreads();

    // ---- final write, d-major: 7-float contiguous w-runs for loads+stores --
    {
        size_t nbase = (size_t)n * CC * HWP;
        int hb = ph*KK, wb = pw*KK;
        for (int i = t; i < CC*DD; i += 512) {
            int c = i / DD, d = i - (i/DD)*DD;
            int kh = d / KK, kw = d - kh*KK;
            int h = hb + kh, w = wb + kw;
            if (h < HH && w < WW) {
                int li = (c*HH + h)*WW + w;
                xe[nbase + li] = s_ex[c*PAD + d] * s_me[d] + exn[li];
                xq[nbase + li] = s_q [c*PAD + d] * s_mq[d] + qn[li];
            }
        }
    }
}

// ---------------------------------------------------------------------------
// Depthwise 3x3 (pad 1) + BN + ReLU. 4 rows x 4 cols per thread.
// ---------------------------------------------------------------------------
__global__ __launch_bounds__(256) void dw_kernel(
    const float* __restrict__ x, float* __restrict__ y,
    const float* __restrict__ wdw, const float* __restrict__ g,
    const float* __restrict__ b, int CoutTot, int coff)
{
    int idx = blockIdx.x * 256 + threadIdx.x;   // NN*CC*32*32 = 1,048,576
    int w4 = (idx & 31) * 4;
    int h4 = ((idx >> 5) & 31) * 4;
    int nc = idx >> 10;
    int c  = nc & 127;
    int n  = nc >> 7;

    const float* wp = wdw + (coff + c) * 9;
    float wr[9];
    #pragma unroll
    for (int i = 0; i < 9; ++i) wr[i] = wp[i];

    const float* base = x + (size_t)nc * HWP;
    float acc[4][4];
    #pragma unroll
    for (int i = 0; i < 4; ++i)
        #pragma unroll
        for (int j = 0; j < 4; ++j) acc[i][j] = 0.f;

    #pragma unroll
    for (int r = 0; r < 6; ++r) {
        int hh = h4 - 1 + r;
        if (hh >= 0 && hh < HH) {
            const float* row = base + hh * WW + w4;
            float4 v = *(const float4*)row;
            float e[6];
            e[0] = (w4 > 0)   ? row[-1] : 0.f;
            e[1] = v.x; e[2] = v.y; e[3] = v.z; e[4] = v.w;
            e[5] = (w4 < 124) ? row[4]  : 0.f;
            int ilo = r - 2 > 0 ? r - 2 : 0;
            int ihi = r < 3 ? r : 3;
            for (int i = ilo; i <= ihi; ++i) {
                int j = r - i;                 // tap row 0..2
                float wa = wr[j*3], wb = wr[j*3+1], wc = wr[j*3+2];
                acc[i][0] += wa*e[0] + wb*e[1] + wc*e[2];
                acc[i][1] += wa*e[1] + wb*e[2] + wc*e[3];
                acc[i][2] += wa*e[2] + wb*e[3] + wc*e[4];
                acc[i][3] += wa*e[3] + wb*e[4] + wc*e[5];
            }
        }
    }
    const float rs = 0.99999500003749968f;   // 1/sqrt(1+1e-5)
    float sc = g[coff + c] * rs, bi = b[coff + c];
    float* outp = y + (((size_t)n * CoutTot + coff + c) * HH + h4) * WW + w4;
    #pragma unroll
    for (int i = 0; i < 4; ++i) {
        float4 o;
        o.x = fmaxf(acc[i][0] * sc + bi, 0.f);
        o.y = fmaxf(acc[i][1] * sc + bi, 0.f);
        o.z = fmaxf(acc[i][2] * sc + bi, 0.f);
        o.w = fmaxf(acc[i][3] * sc + bi, 0.f);
        *(float4*)(outp + i * WW) = o;
    }
}

// ---------------------------------------------------------------------------
// Pointwise 1x1 (Cin -> 128) + BN + ReLU, GEMM-tiled.
// Block: 128 out-ch x 128 px; thread: 8x8; k staged in 32-channel LDS chunks.
// ---------------------------------------------------------------------------
__global__ __launch_bounds__(256, 4) void pw_kernel(
    const float* __restrict__ z, float* __restrict__ out,
    const float* __restrict__ Wp, const float* __restrict__ g,
    const float* __restrict__ b, int Cin)
{
    __shared__ float s_w[32*130];   // [cc][o]  pad 130
    __shared__ float s_a[32*132];   // [cc][px] pad 132
    const int t  = threadIdx.x;
    const int n  = blockIdx.y;
    const int p0 = blockIdx.x * 128;
    const int o0  = (t >> 4) * 8;
    const int px0 = (t & 15) * 8;

    float acc[8][8];
    #pragma unroll
    for (int i = 0; i < 8; ++i)
        #pragma unroll
        for (int j = 0; j < 8; ++j) acc[i][j] = 0.f;

    const float* zn = z + (size_t)n * Cin * HWP;
    const int nch = Cin >> 5;
    for (int cb = 0; cb < nch; ++cb) {
        for (int i = t; i < 128*32; i += 256) {     // weights
            int o = i >> 5, cc = i & 31;
            s_w[cc*130 + o] = Wp[o*Cin + cb*32 + cc];
        }
        for (int i = t; i < 32*128; i += 256) {     // activations
            int cc = i >> 7, px = i & 127;
            s_a[cc*132 + px] = zn[(cb*32 + cc)*HWP + p0 + px];
        }
        __syncthreads();
        #pragma unroll 4
        for (int cc = 0; cc < 32; ++cc) {
            float4 w0 = *(const float4*)&s_w[cc*130 + o0];
            float4 w1 = *(const float4*)&s_w[cc*130 + o0 + 4];
            float4 a0 = *(const float4*)&s_a[cc*132 + px0];
            float4 a1 = *(const float4*)&s_a[cc*132 + px0 + 4];
            float wv[8] = {w0.x,w0.y,w0.z,w0.w, w1.x,w1.y,w1.z,w1.w};
            float av[8] = {a0.x,a0.y,a0.z,a0.w, a1.x,a1.y,a1.z,a1.w};
            #pragma unroll
            for (int i = 0; i < 8; ++i)
                #pragma unroll
                for (int j = 0; j < 8; ++j)
                    acc[i][j] = fmaf(wv[i], av[j], acc[i][j]);
        }
        __syncthreads();
    }
    const float rs = 0.99999500003749968f;
    float* on = out + (size_t)n * 128 * HWP;
    #pragma unroll
    for (int i = 0; i < 8; ++i) {
        int o = o0 + i;
        float sc = g[o] * rs, bi = b[o];
        float4 v0, v1;
        v0.x = fmaxf(acc[i][0]*sc + bi, 0.f);
        v0.y = fmaxf(acc[i][1]*sc + bi, 0.f);
        v0.z = fmaxf(acc[i][2]*sc + bi, 0.f);
        v0.w = fmaxf(acc[i][3]*sc + bi, 0.f);
        v1.x = fmaxf(acc[i][4]*sc + bi, 0.f);
        v1.y = fmaxf(acc[i][5]*sc + bi, 0.f);
        v1.z = fmaxf(acc[i][6]*sc + bi, 0.f);
        v1.w = fmaxf(acc[i][7]*sc + bi, 0.f);
        *(float4*)&on[o*HWP + p0 + px0]     = v0;
        *(float4*)&on[o*HWP + p0 + px0 + 4] = v1;
    }
}

// ---------------------------------------------------------------------------
extern "C" void kernel_launch(void* const* d_in, const int* in_sizes, int n_in,
                              void* d_out, int out_size, void* d_ws, size_t ws_size,
                              hipStream_t stream) {
    const float* exemplar = (const float*)d_in[0];
    const float* query    = (const float*)d_in[1];
    const float* w_conv_e = (const float*)d_in[2];
    const float* w_gate1  = (const float*)d_in[3];
    const float* w_gate2  = (const float*)d_in[4];
    const float* dw1_w    = (const float*)d_in[5];
    const float* bn1a_g   = (const float*)d_in[6];
    const float* bn1a_b   = (const float*)d_in[7];
    const float* pw1_w    = (const float*)d_in[8];
    const float* bn1b_g   = (const float*)d_in[9];
    const float* bn1b_b   = (const float*)d_in[10];
    const float* dwf_w    = (const float*)d_in[11];
    const float* bnfa_g   = (const float*)d_in[12];
    const float* bnfa_b   = (const float*)d_in[13];
    const float* pwf_w    = (const float*)d_in[14];
    const float* bnfb_g   = (const float*)d_in[15];
    const float* bnfb_b   = (const float*)d_in[16];

    float* out = (float*)d_out;
    float* ws  = (float*)d_ws;
    const size_t SZ = (size_t)NN * CC * HWP;     // 16,777,216 floats
    float* bufA = ws;              // x_e -> e_out
    float* bufB = ws + SZ;         // x_q -> q_out
    float* bufC = ws + 2 * SZ;     // z_e; later T (spans 2*SZ as (N,256,H,W))
    float* bufD = ws + 3 * SZ;     // z_q
    float* T    = bufC;

    // 1) fused attention + gating + residual
    attn_kernel<<<dim3(PHN * PHN, NN), 512, 0, stream>>>(
        exemplar, query, w_conv_e, w_gate1, w_gate2, bufA, bufB);

    // 2) dsconv #1 depthwise
    dw_kernel<<<4096, 256, 0, stream>>>(bufA, bufC, dw1_w, bn1a_g, bn1a_b, 128, 0);
    dw_kernel<<<4096, 256, 0, stream>>>(bufB, bufD, dw1_w, bn1a_g, bn1a_b, 128, 0);

    // 3) dsconv #1 pointwise
    pw_kernel<<<dim3(128, NN), 256, 0, stream>>>(bufC, bufA, pw1_w, bn1b_g, bn1b_b, 128);
    pw_kernel<<<dim3(128, NN), 256, 0, stream>>>(bufD, bufB, pw1_w, bn1b_g, bn1b_b, 128);

    // 4) final depthwise on concat (writes (N,256,H,W) layout directly)
    dw_kernel<<<4096, 256, 0, stream>>>(bufA, T, dwf_w, bnfa_g, bnfa_b, 256, 0);
    dw_kernel<<<4096, 256, 0, stream>>>(bufB, T, dwf_w, bnfa_g, bnfa_b, 256, 128);

    // 5) final pointwise 256 -> 128
    pw_kernel<<<dim3(128, NN), 256, 0, stream>>>(T, out, pwf_w, bnfb_g, bnfb_b, 256);
}

// Round 5
// 842.206 us; speedup vs baseline: 2.1697x; 1.1197x over previous
//
#include <hip/hip_runtime.h>
#include <hip/hip_bf16.h>

#define NN 8
#define CC 128
#define HH 128
#define WW 128
#define HWP (HH*WW)
#define KK 7
#define DD 49
#define NPH 31
#define NPATCH 961
#define PHN 19
#define PAD 52
#define PP2 (PAD*PAD)

__global__ __launch_bounds__(512, 4) void attn_kernel(
    const float* __restrict__ ex_g, const float* __restrict__ q_g,
    const float* __restrict__ Wce, const float* __restrict__ wg1,
    const float* __restrict__ wg2,
    float* __restrict__ xe, float* __restrict__ xq)
{
    __shared__ float s_ex[CC*PAD];
    __shared__ float s_q [CC*PAD];
    __shared__ float s_scr[CC*PAD];
    __shared__ float s_m1[PAD], s_l1[PAD], s_m2[PAD], s_l2[PAD];
    __shared__ float s_g1[PAD], s_g2[PAD], s_me[PAD], s_mq[PAD];

    const int t  = threadIdx.x;
    const int n  = blockIdx.y;
    const int ph = blockIdx.x / PHN;
    const int pw = blockIdx.x % PHN;
    const int pp = (ph * NPH + pw) * CC;

    const float* exn = ex_g + (size_t)n * CC * HWP;
    const float* qn  = q_g  + (size_t)n * CC * HWP;

    for (int i = t; i < CC*DD; i += 512) {
        int c2 = i / DD, d = i - c2*DD;
        int kh = d / KK, kw = d - kh*KK;
        int rem  = pp + c2;
        int c_u  = rem / NPATCH;
        int p_u  = rem - c_u * NPATCH;
        int ph_u = p_u / NPH;
        int pw_u = p_u - ph_u * NPH;
        int gi = (c_u*HH + ph_u*4 + kh)*WW + pw_u*4 + kw;
        s_ex[c2*PAD + d] = exn[gi];
        s_q [c2*PAD + d] = qn [gi];
    }
    if (t < CC*3) {
        int c = t / 3, j = t - (t/3)*3;
        s_ex[c*PAD + DD + j] = 0.f;
        s_q [c*PAD + DD + j] = 0.f;
    }
    __syncthreads();

    // ec = Wce @ ex
    {
        const int eg_o = t / 13, eg_d = t - (t/13)*13;
        const int o0 = eg_o*4, d0 = eg_d*4;
        float ac[4][4];
        #pragma unroll
        for (int i = 0; i < 4; ++i)
            #pragma unroll
            for (int j = 0; j < 4; ++j) ac[i][j] = 0.f;
        if (t < 416) {
            for (int k = 0; k < CC; k += 4) {
                float xm[4][4];
                #pragma unroll
                for (int kk = 0; kk < 4; ++kk) {
                    float4 xv = *(const float4*)&s_ex[(k+kk)*PAD + d0];
                    xm[kk][0]=xv.x; xm[kk][1]=xv.y; xm[kk][2]=xv.z; xm[kk][3]=xv.w;
                }
                #pragma unroll
                for (int i = 0; i < 4; ++i) {
                    float4 wv = *(const float4*)&Wce[(o0+i)*CC + k];
                    float wr[4] = {wv.x, wv.y, wv.z, wv.w};
                    #pragma unroll
                    for (int kk = 0; kk < 4; ++kk)
                        #pragma unroll
                        for (int j = 0; j < 4; ++j)
                            ac[i][j] = fmaf(wr[kk], xm[kk][j], ac[i][j]);
                }
            }
        }
        __syncthreads();
        if (t < 416) {
            #pragma unroll
            for (int i = 0; i < 4; ++i)
                *(float4*)&s_scr[(o0+i)*PAD + d0] =
                    make_float4(ac[i][0], ac[i][1], ac[i][2], ac[i][3]);
        }
    }
    __syncthreads();

    // A = ec^T-contract, 338 threads 4d x 2e; gates on spare threads
    float aa[4][2];
    int ad0 = 0, ae0 = 0;
    if (t < 338) {
        int dg = t % 13, eg = t / 13;
        ad0 = dg*4; ae0 = eg*2;
        #pragma unroll
        for (int i = 0; i < 4; ++i) { aa[i][0] = 0.f; aa[i][1] = 0.f; }
        #pragma unroll 4
        for (int k = 0; k < CC; ++k) {
            float4 ev = *(const float4*)&s_scr[k*PAD + ad0];
            float2 qv = *(const float2*)&s_q [k*PAD + ae0];
            #pragma unroll
            for (int i = 0; i < 4; ++i) {
                float e = (i==0)?ev.x:(i==1)?ev.y:(i==2)?ev.z:ev.w;
                aa[i][0] = fmaf(e, qv.x, aa[i][0]);
                aa[i][1] = fmaf(e, qv.y, aa[i][1]);
            }
        }
    } else if (t >= 352 && t < 352 + DD) {
        int e = t - 352;
        float acc = 0.f;
        for (int c = 0; c < CC; ++c) acc = fmaf(wg1[c], s_q[c*PAD + e], acc);
        s_g1[e] = acc;
    } else if (t >= 416 && t < 416 + DD) {
        int d = t - 416;
        float acc = 0.f;
        for (int c = 0; c < CC; ++c) acc = fmaf(wg2[c], s_ex[c*PAD + d], acc);
        s_g2[d] = acc;
    }
    __syncthreads();
    if (t < 338) {
        #pragma unroll
        for (int i = 0; i < 4; ++i)
            *(float2*)&s_scr[(ad0+i)*PAD + ae0] = make_float2(aa[i][0], aa[i][1]);
    }
    __syncthreads();

    // softmax stats
    if (t < PAD) {
        if (t < DD) {
            float m = -1e30f;
            for (int d = 0; d < DD; ++d) m = fmaxf(m, s_scr[d*PAD + t]);
            float l = 0.f;
            for (int d = 0; d < DD; ++d) l += __expf(s_scr[d*PAD + t] - m);
            s_m1[t] = m; s_l1[t] = 1.f / l;
        } else { s_m1[t] = 0.f; s_l1[t] = 0.f; }
    } else if (t >= 64 && t < 64 + PAD) {
        int d = t - 64;
        if (d < DD) {
            float m = -1e30f;
            for (int e = 0; e < DD; ++e) m = fmaxf(m, s_scr[d*PAD + e]);
            float l = 0.f;
            for (int e = 0; e < DD; ++e) l += __expf(s_scr[d*PAD + e] - m);
            s_m2[d] = m; s_l2[d] = 1.f / l;
        } else { s_m2[d] = 0.f; s_l2[d] = 0.f; }
    }
    __syncthreads();

    // P build: P1[d][e] to upper scr; P2T[e][d] in-place via snapshot
    float* P1  = s_scr + PP2;
    float* P2T = s_scr;
    {
        float p2buf[6]; int nv = 0;
        for (int i = t; i < PP2; i += 512) {
            int d = i / PAD, e = i - d*PAD;
            float a = s_scr[i];
            P1[i] = __expf(a - s_m1[e]) * s_l1[e];
            p2buf[nv++] = __expf(a - s_m2[d]) * s_l2[d];
        }
        __syncthreads();
        nv = 0;
        for (int i = t; i < PP2; i += 512) {
            int d = i / PAD, e = i - d*PAD;
            P2T[e*PAD + d] = p2buf[nv++];
        }
    }
    __syncthreads();

    // gates
    if (t < PAD) {
        if (t < DD) {
            float a1 = 0.f, a2 = 0.f;
            for (int e = 0; e < DD; ++e)  a1 = fmaf(s_g1[e],  P2T[e*PAD + t], a1);
            s_me[t] = 1.f / (1.f + __expf(-a1));
            for (int dd = 0; dd < DD; ++dd) a2 = fmaf(s_g2[dd], P1[dd*PAD + t], a2);
            s_mq[t] = 1.f / (1.f + __expf(-a2));
        } else { s_me[t] = 0.f; s_mq[t] = 0.f; }
    }
    __syncthreads();

    // output GEMMs, k-step 4, all-float4
    float ae[4][4], aq[4][4];
    int c0 = 0, x0 = 0;
    if (t < 416) {
        int cg = t / 13, xg = t - (t/13)*13;
        c0 = cg*4; x0 = xg*4;
        #pragma unroll
        for (int i = 0; i < 4; ++i)
            #pragma unroll
            for (int j = 0; j < 4; ++j) { ae[i][j] = 0.f; aq[i][j] = 0.f; }
        for (int k = 0; k < 48; k += 4) {
            float qm[4][4], xm[4][4], p1m[4][4], p2m[4][4];
            #pragma unroll
            for (int i = 0; i < 4; ++i) {
                float4 qv = *(const float4*)&s_q [(c0+i)*PAD + k];
                float4 xv = *(const float4*)&s_ex[(c0+i)*PAD + k];
                qm[i][0]=qv.x; qm[i][1]=qv.y; qm[i][2]=qv.z; qm[i][3]=qv.w;
                xm[i][0]=xv.x; xm[i][1]=xv.y; xm[i][2]=xv.z; xm[i][3]=xv.w;
            }
            #pragma unroll
            for (int kk = 0; kk < 4; ++kk) {
                float4 p1 = *(const float4*)&P1 [(k+kk)*PAD + x0];
                float4 p2 = *(const float4*)&P2T[(k+kk)*PAD + x0];
                p1m[kk][0]=p1.x; p1m[kk][1]=p1.y; p1m[kk][2]=p1.z; p1m[kk][3]=p1.w;
                p2m[kk][0]=p2.x; p2m[kk][1]=p2.y; p2m[kk][2]=p2.z; p2m[kk][3]=p2.w;
            }
            #pragma unroll
            for (int kk = 0; kk < 4; ++kk)
                #pragma unroll
                for (int i = 0; i < 4; ++i)
                    #pragma unroll
                    for (int j = 0; j < 4; ++j) {
                        ae[i][j] = fmaf(qm[i][kk], p2m[kk][j], ae[i][j]);
                        aq[i][j] = fmaf(xm[i][kk], p1m[kk][j], aq[i][j]);
                    }
        }
        {
            const int k = 48;
            float p1r[4], p2r[4];
            #pragma unroll
            for (int j = 0; j < 4; ++j) { p1r[j] = P1 [k*PAD + x0 + j];
                                          p2r[j] = P2T[k*PAD + x0 + j]; }
            #pragma unroll
            for (int i = 0; i < 4; ++i) {
                float qv = s_q [(c0+i)*PAD + k];
                float xv = s_ex[(c0+i)*PAD + k];
                #pragma unroll
                for (int j = 0; j < 4; ++j) {
                    ae[i][j] = fmaf(qv, p2r[j], ae[i][j]);
                    aq[i][j] = fmaf(xv, p1r[j], aq[i][j]);
                }
            }
        }
    }
    __syncthreads();
    if (t < 416) {
        #pragma unroll
        for (int i = 0; i < 4; ++i) {
            *(float4*)&s_ex[(c0+i)*PAD + x0] =
                make_float4(ae[i][0], ae[i][1], ae[i][2], ae[i][3]);
            *(float4*)&s_q [(c0+i)*PAD + x0] =
                make_float4(aq[i][0], aq[i][1], aq[i][2], aq[i][3]);
        }
    }
    __syncthreads();

    {
        size_t nbase = (size_t)n * CC * HWP;
        int hb = ph*KK, wb = pw*KK;
        for (int i = t; i < CC*DD; i += 512) {
            int c = i / DD, d = i - (i/DD)*DD;
            int kh = d / KK, kw = d - kh*KK;
            int h = hb + kh, w = wb + kw;
            if (h < HH && w < WW) {
                int li = (c*HH + h)*WW + w;
                xe[nbase + li] = s_ex[c*PAD + d] * s_me[d] + exn[li];
                xq[nbase + li] = s_q [c*PAD + d] * s_mq[d] + qn[li];
            }
        }
    }
}

__global__ __launch_bounds__(256) void dw2_kernel(
    const float* __restrict__ xA, float* __restrict__ yA,
    const float* __restrict__ xB, float* __restrict__ yB,
    const float* __restrict__ wdw, const float* __restrict__ g,
    const float* __restrict__ b, int CoutTot, int coffA, int coffB)
{
    int bid = blockIdx.x;
    int sel = bid >> 12;
    int idx = (bid & 4095) * 256 + threadIdx.x;
    const float* x = sel ? xB : xA;
    float*       y = sel ? yB : yA;
    int coff       = sel ? coffB : coffA;

    int w4 = (idx & 31) * 4;
    int h4 = ((idx >> 5) & 31) * 4;
    int nc = idx >> 10;
    int c  = nc & 127;
    int n  = nc >> 7;

    const float* wp = wdw + (coff + c) * 9;
    float wr[9];
    #pragma unroll
    for (int i = 0; i < 9; ++i) wr[i] = wp[i];

    const float* base = x + (size_t)nc * HWP;
    float acc[4][4];
    #pragma unroll
    for (int i = 0; i < 4; ++i)
        #pragma unroll
        for (int j = 0; j < 4; ++j) acc[i][j] = 0.f;

    #pragma unroll
    for (int r = 0; r < 6; ++r) {
        int hh = h4 - 1 + r;
        if (hh >= 0 && hh < HH) {
            const float* row = base + hh * WW + w4;
            float4 v = *(const float4*)row;
            float e[6];
            e[0] = (w4 > 0)   ? row[-1] : 0.f;
            e[1] = v.x; e[2] = v.y; e[3] = v.z; e[4] = v.w;
            e[5] = (w4 < 124) ? row[4]  : 0.f;
            int ilo = r - 2 > 0 ? r - 2 : 0;
            int ihi = r < 3 ? r : 3;
            for (int i = ilo; i <= ihi; ++i) {
                int j = r - i;
                float wa = wr[j*3], wb = wr[j*3+1], wc = wr[j*3+2];
                acc[i][0] += wa*e[0] + wb*e[1] + wc*e[2];
                acc[i][1] += wa*e[1] + wb*e[2] + wc*e[3];
                acc[i][2] += wa*e[2] + wb*e[3] + wc*e[4];
                acc[i][3] += wa*e[3] + wb*e[4] + wc*e[5];
            }
        }
    }
    const float rs = 0.99999500003749968f;
    float sc = g[coff + c] * rs, bi = b[coff + c];
    float* outp = y + (((size_t)n * CoutTot + coff + c) * HH + h4) * WW + w4;
    #pragma unroll
    for (int i = 0; i < 4; ++i) {
        float4 o;
        o.x = fmaxf(acc[i][0] * sc + bi, 0.f);
        o.y = fmaxf(acc[i][1] * sc + bi, 0.f);
        o.z = fmaxf(acc[i][2] * sc + bi, 0.f);
        o.w = fmaxf(acc[i][3] * sc + bi, 0.f);
        *(float4*)(outp + i * WW) = o;
    }
}

__global__ __launch_bounds__(256, 4) void pw_kernel(
    const float* __restrict__ zA, float* __restrict__ outA,
    const float* __restrict__ zB, float* __restrict__ outB,
    const float* __restrict__ Wp, const float* __restrict__ g,
    const float* __restrict__ b, int Cin)
{
    __shared__ float s_w[32*130];
    __shared__ float s_a[32*132];
    const int t  = threadIdx.x;
    const int n  = blockIdx.y;
    const int p0 = blockIdx.x * 128;
    const float* z   = blockIdx.z ? zB   : zA;
    float*       out = blockIdx.z ? outB : outA;
    const int o0  = (t >> 4) * 8;
    const int px0 = (t & 15) * 8;

    float acc[8][8];
    #pragma unroll
    for (int i = 0; i < 8; ++i)
        #pragma unroll
        for (int j = 0; j < 8; ++j) acc[i][j] = 0.f;

    const float* zn = z + (size_t)n * Cin * HWP;
    const int nch = Cin >> 5;
    for (int cb = 0; cb < nch; ++cb) {
        for (int i = t; i < 128*32; i += 256) {
            int o = i >> 5, cc = i & 31;
            s_w[cc*130 + o] = Wp[o*Cin + cb*32 + cc];
        }
        for (int i = t; i < 32*128; i += 256) {
            int cc = i >> 7, px = i & 127;
            s_a[cc*132 + px] = zn[(cb*32 + cc)*HWP + p0 + px];
        }
        __syncthreads();
        #pragma unroll 4
        for (int cc = 0; cc < 32; ++cc) {
            float4 w0 = *(const float4*)&s_w[cc*130 + o0];
            float4 w1 = *(const float4*)&s_w[cc*130 + o0 + 4];
            float4 a0 = *(const float4*)&s_a[cc*132 + px0];
            float4 a1 = *(const float4*)&s_a[cc*132 + px0 + 4];
            float wv[8] = {w0.x,w0.y,w0.z,w0.w, w1.x,w1.y,w1.z,w1.w};
            float av[8] = {a0.x,a0.y,a0.z,a0.w, a1.x,a1.y,a1.z,a1.w};
            #pragma unroll
            for (int i = 0; i < 8; ++i)
                #pragma unroll
                for (int j = 0; j < 8; ++j)
                    acc[i][j] = fmaf(wv[i], av[j], acc[i][j]);
        }
        __syncthreads();
    }
    const float rs = 0.99999500003749968f;
    float* on = out + (size_t)n * 128 * HWP;
    #pragma unroll
    for (int i = 0; i < 8; ++i) {
        int o = o0 + i;
        float sc = g[o] * rs, bi = b[o];
        float4 v0, v1;
        v0.x = fmaxf(acc[i][0]*sc + bi, 0.f);
        v0.y = fmaxf(acc[i][1]*sc + bi, 0.f);
        v0.z = fmaxf(acc[i][2]*sc + bi, 0.f);
        v0.w = fmaxf(acc[i][3]*sc + bi, 0.f);
        v1.x = fmaxf(acc[i][4]*sc + bi, 0.f);
        v1.y = fmaxf(acc[i][5]*sc + bi, 0.f);
        v1.z = fmaxf(acc[i][6]*sc + bi, 0.f);
        v1.w = fmaxf(acc[i][7]*sc + bi, 0.f);
        *(float4*)&on[o*HWP + p0 + px0]     = v0;
        *(float4*)&on[o*HWP + p0 + px0 + 4] = v1;
    }
}

extern "C" void kernel_launch(void* const* d_in, const int* in_sizes, int n_in,
                              void* d_out, int out_size, void* d_ws, size_t ws_size,
                              hipStream_t stream) {
    const float* exemplar = (const float*)d_in[0];
    const float* query    = (const float*)d_in[1];
    const float* w_conv_e = (const float*)d_in[2];
    const float* w_gate1  = (const float*)d_in[3];
    const float* w_gate2  = (const float*)d_in[4];
    const float* dw1_w    = (const float*)d_in[5];
    const float* bn1a_g   = (const float*)d_in[6];
    const float* bn1a_b   = (const float*)d_in[7];
    const float* pw1_w    = (const float*)d_in[8];
    const float* bn1b_g   = (const float*)d_in[9];
    const float* bn1b_b   = (const float*)d_in[10];
    const float* dwf_w    = (const float*)d_in[11];
    const float* bnfa_g   = (const float*)d_in[12];
    const float* bnfa_b   = (const float*)d_in[13];
    const float* pwf_w    = (const float*)d_in[14];
    const float* bnfb_g   = (const float*)d_in[15];
    const float* bnfb_b   = (const float*)d_in[16];

    float* out = (float*)d_out;
    float* ws  = (float*)d_ws;
    const size_t SZ = (size_t)NN * CC * HWP;
    float* bufA = ws;
    float* bufB = ws + SZ;
    float* bufC = ws + 2 * SZ;
    float* bufD = ws + 3 * SZ;
    float* T    = bufC;

    attn_kernel<<<dim3(PHN * PHN, NN), 512, 0, stream>>>(
        exemplar, query, w_conv_e, w_gate1, w_gate2, bufA, bufB);

    dw2_kernel<<<8192, 256, 0, stream>>>(bufA, bufC, bufB, bufD,
                                         dw1_w, bn1a_g, bn1a_b, 128, 0, 0);

    pw_kernel<<<dim3(128, NN, 2), 256, 0, stream>>>(bufC, bufA, bufD, bufB,
                                                    pw1_w, bn1b_g, bn1b_b, 128);

    dw2_kernel<<<8192, 256, 0, stream>>>(bufA, T, bufB, T,
                                         dwf_w, bnfa_g, bnfa_b, 256, 0, 128);

    pw_kernel<<<dim3(128, NN, 1), 256, 0, stream>>>(T, out, nullptr, nullptr,
                                                    pwf_w, bnfb_g, bnfb_b, 256);
}

// Round 6
// 712.551 us; speedup vs baseline: 2.5645x; 1.1820x over previous
//
#include <hip/hip_runtime.h>
#include <hip/hip_bf16.h>

#define NN 8
#define CC 128
#define HH 128
#define WW 128
#define HWP (HH*WW)
#define KK 7
#define DD 49
#define NPH 31
#define NPATCH 961
#define PHN 19
#define PAD 52
#define PP2 (PAD*PAD)

typedef __attribute__((ext_vector_type(8))) short bf16x8;
typedef __attribute__((ext_vector_type(4))) float f32x4;
typedef __attribute__((ext_vector_type(4))) unsigned short us4;

__device__ __forceinline__ unsigned short f2bf(float f) {
    unsigned u = __builtin_bit_cast(unsigned, f);
    return (unsigned short)((u + 0x7FFFu + ((u >> 16) & 1u)) >> 16);   // RNE
}

// ---------------------------------------------------------------------------
// Fused per-patch attention (unchanged math from passing R5; gather remapped
// to lane-aligned rows: wave = one c2 row -> coalesced 7x28B runs, no div49).
// ---------------------------------------------------------------------------
__global__ __launch_bounds__(512, 4) void attn_kernel(
    const float* __restrict__ ex_g, const float* __restrict__ q_g,
    const float* __restrict__ Wce, const float* __restrict__ wg1,
    const float* __restrict__ wg2,
    float* __restrict__ xe, float* __restrict__ xq)
{
    __shared__ float s_ex[CC*PAD];
    __shared__ float s_q [CC*PAD];
    __shared__ float s_scr[CC*PAD];
    __shared__ float s_m1[PAD], s_l1[PAD], s_m2[PAD], s_l2[PAD];
    __shared__ float s_g1[PAD], s_g2[PAD], s_me[PAD], s_mq[PAD];

    const int t  = threadIdx.x;
    const int n  = blockIdx.y;
    const int ph = blockIdx.x / PHN;
    const int pw = blockIdx.x % PHN;
    const int pp = (ph * NPH + pw) * CC;

    const float* exn = ex_g + (size_t)n * CC * HWP;
    const float* qn  = q_g  + (size_t)n * CC * HWP;

    for (int i = t; i < CC*64; i += 512) {
        int c2 = i >> 6, dl = i & 63;
        if (dl < DD) {
            int kh = dl / KK, kw2 = dl - kh*KK;
            int rem  = pp + c2;
            int c_u  = rem / NPATCH;
            int p_u  = rem - c_u * NPATCH;
            int ph_u = p_u / NPH;
            int pw_u = p_u - ph_u * NPH;
            int gi = (c_u*HH + ph_u*4 + kh)*WW + pw_u*4 + kw2;
            s_ex[c2*PAD + dl] = exn[gi];
            s_q [c2*PAD + dl] = qn [gi];
        }
    }
    if (t < CC*3) {
        int c = t / 3, j = t - (t/3)*3;
        s_ex[c*PAD + DD + j] = 0.f;
        s_q [c*PAD + DD + j] = 0.f;
    }
    __syncthreads();

    // ec = Wce @ ex
    {
        const int eg_o = t / 13, eg_d = t - (t/13)*13;
        const int o0 = eg_o*4, d0 = eg_d*4;
        float ac[4][4];
        #pragma unroll
        for (int i = 0; i < 4; ++i)
            #pragma unroll
            for (int j = 0; j < 4; ++j) ac[i][j] = 0.f;
        if (t < 416) {
            for (int k = 0; k < CC; k += 4) {
                float xm[4][4];
                #pragma unroll
                for (int kk = 0; kk < 4; ++kk) {
                    float4 xv = *(const float4*)&s_ex[(k+kk)*PAD + d0];
                    xm[kk][0]=xv.x; xm[kk][1]=xv.y; xm[kk][2]=xv.z; xm[kk][3]=xv.w;
                }
                #pragma unroll
                for (int i = 0; i < 4; ++i) {
                    float4 wv = *(const float4*)&Wce[(o0+i)*CC + k];
                    float wr[4] = {wv.x, wv.y, wv.z, wv.w};
                    #pragma unroll
                    for (int kk = 0; kk < 4; ++kk)
                        #pragma unroll
                        for (int j = 0; j < 4; ++j)
                            ac[i][j] = fmaf(wr[kk], xm[kk][j], ac[i][j]);
                }
            }
        }
        __syncthreads();
        if (t < 416) {
            #pragma unroll
            for (int i = 0; i < 4; ++i)
                *(float4*)&s_scr[(o0+i)*PAD + d0] =
                    make_float4(ac[i][0], ac[i][1], ac[i][2], ac[i][3]);
        }
    }
    __syncthreads();

    // A = ec^T q, 338 threads 4d x 2e; gates on spare threads
    float aa[4][2];
    int ad0 = 0, ae0 = 0;
    if (t < 338) {
        int dg = t % 13, eg = t / 13;
        ad0 = dg*4; ae0 = eg*2;
        #pragma unroll
        for (int i = 0; i < 4; ++i) { aa[i][0] = 0.f; aa[i][1] = 0.f; }
        #pragma unroll 4
        for (int k = 0; k < CC; ++k) {
            float4 ev = *(const float4*)&s_scr[k*PAD + ad0];
            float2 qv = *(const float2*)&s_q [k*PAD + ae0];
            #pragma unroll
            for (int i = 0; i < 4; ++i) {
                float e = (i==0)?ev.x:(i==1)?ev.y:(i==2)?ev.z:ev.w;
                aa[i][0] = fmaf(e, qv.x, aa[i][0]);
                aa[i][1] = fmaf(e, qv.y, aa[i][1]);
            }
        }
    } else if (t >= 352 && t < 352 + DD) {
        int e = t - 352;
        float acc = 0.f;
        for (int c = 0; c < CC; ++c) acc = fmaf(wg1[c], s_q[c*PAD + e], acc);
        s_g1[e] = acc;
    } else if (t >= 416 && t < 416 + DD) {
        int d = t - 416;
        float acc = 0.f;
        for (int c = 0; c < CC; ++c) acc = fmaf(wg2[c], s_ex[c*PAD + d], acc);
        s_g2[d] = acc;
    }
    __syncthreads();
    if (t < 338) {
        #pragma unroll
        for (int i = 0; i < 4; ++i)
            *(float2*)&s_scr[(ad0+i)*PAD + ae0] = make_float2(aa[i][0], aa[i][1]);
    }
    __syncthreads();

    // softmax stats
    if (t < PAD) {
        if (t < DD) {
            float m = -1e30f;
            for (int d = 0; d < DD; ++d) m = fmaxf(m, s_scr[d*PAD + t]);
            float l = 0.f;
            for (int d = 0; d < DD; ++d) l += __expf(s_scr[d*PAD + t] - m);
            s_m1[t] = m; s_l1[t] = 1.f / l;
        } else { s_m1[t] = 0.f; s_l1[t] = 0.f; }
    } else if (t >= 64 && t < 64 + PAD) {
        int d = t - 64;
        if (d < DD) {
            float m = -1e30f;
            for (int e = 0; e < DD; ++e) m = fmaxf(m, s_scr[d*PAD + e]);
            float l = 0.f;
            for (int e = 0; e < DD; ++e) l += __expf(s_scr[d*PAD + e] - m);
            s_m2[d] = m; s_l2[d] = 1.f / l;
        } else { s_m2[d] = 0.f; s_l2[d] = 0.f; }
    }
    __syncthreads();

    // P build: P1[d][e] upper scr; P2T[e][d] in-place via register snapshot
    float* P1  = s_scr + PP2;
    float* P2T = s_scr;
    {
        float p2buf[6]; int nv = 0;
        for (int i = t; i < PP2; i += 512) {
            int d = i / PAD, e = i - d*PAD;
            float a = s_scr[i];
            P1[i] = __expf(a - s_m1[e]) * s_l1[e];
            p2buf[nv++] = __expf(a - s_m2[d]) * s_l2[d];
        }
        __syncthreads();
        nv = 0;
        for (int i = t; i < PP2; i += 512) {
            int d = i / PAD, e = i - d*PAD;
            P2T[e*PAD + d] = p2buf[nv++];
        }
    }
    __syncthreads();

    // gates
    if (t < PAD) {
        if (t < DD) {
            float a1 = 0.f, a2 = 0.f;
            for (int e = 0; e < DD; ++e)  a1 = fmaf(s_g1[e],  P2T[e*PAD + t], a1);
            s_me[t] = 1.f / (1.f + __expf(-a1));
            for (int dd = 0; dd < DD; ++dd) a2 = fmaf(s_g2[dd], P1[dd*PAD + t], a2);
            s_mq[t] = 1.f / (1.f + __expf(-a2));
        } else { s_me[t] = 0.f; s_mq[t] = 0.f; }
    }
    __syncthreads();

    // output GEMMs, k-step 4, all-float4
    float ae[4][4], aq[4][4];
    int c0 = 0, x0 = 0;
    if (t < 416) {
        int cg = t / 13, xg = t - (t/13)*13;
        c0 = cg*4; x0 = xg*4;
        #pragma unroll
        for (int i = 0; i < 4; ++i)
            #pragma unroll
            for (int j = 0; j < 4; ++j) { ae[i][j] = 0.f; aq[i][j] = 0.f; }
        for (int k = 0; k < 48; k += 4) {
            float qm[4][4], xm[4][4], p1m[4][4], p2m[4][4];
            #pragma unroll
            for (int i = 0; i < 4; ++i) {
                float4 qv = *(const float4*)&s_q [(c0+i)*PAD + k];
                float4 xv = *(const float4*)&s_ex[(c0+i)*PAD + k];
                qm[i][0]=qv.x; qm[i][1]=qv.y; qm[i][2]=qv.z; qm[i][3]=qv.w;
                xm[i][0]=xv.x; xm[i][1]=xv.y; xm[i][2]=xv.z; xm[i][3]=xv.w;
            }
            #pragma unroll
            for (int kk = 0; kk < 4; ++kk) {
                float4 p1 = *(const float4*)&P1 [(k+kk)*PAD + x0];
                float4 p2 = *(const float4*)&P2T[(k+kk)*PAD + x0];
                p1m[kk][0]=p1.x; p1m[kk][1]=p1.y; p1m[kk][2]=p1.z; p1m[kk][3]=p1.w;
                p2m[kk][0]=p2.x; p2m[kk][1]=p2.y; p2m[kk][2]=p2.z; p2m[kk][3]=p2.w;
            }
            #pragma unroll
            for (int kk = 0; kk < 4; ++kk)
                #pragma unroll
                for (int i = 0; i < 4; ++i)
                    #pragma unroll
                    for (int j = 0; j < 4; ++j) {
                        ae[i][j] = fmaf(qm[i][kk], p2m[kk][j], ae[i][j]);
                        aq[i][j] = fmaf(xm[i][kk], p1m[kk][j], aq[i][j]);
                    }
        }
        {
            const int k = 48;
            float p1r[4], p2r[4];
            #pragma unroll
            for (int j = 0; j < 4; ++j) { p1r[j] = P1 [k*PAD + x0 + j];
                                          p2r[j] = P2T[k*PAD + x0 + j]; }
            #pragma unroll
            for (int i = 0; i < 4; ++i) {
                float qv = s_q [(c0+i)*PAD + k];
                float xv = s_ex[(c0+i)*PAD + k];
                #pragma unroll
                for (int j = 0; j < 4; ++j) {
                    ae[i][j] = fmaf(qv, p2r[j], ae[i][j]);
                    aq[i][j] = fmaf(xv, p1r[j], aq[i][j]);
                }
            }
        }
    }
    __syncthreads();
    if (t < 416) {
        #pragma unroll
        for (int i = 0; i < 4; ++i) {
            *(float4*)&s_ex[(c0+i)*PAD + x0] =
                make_float4(ae[i][0], ae[i][1], ae[i][2], ae[i][3]);
            *(float4*)&s_q [(c0+i)*PAD + x0] =
                make_float4(aq[i][0], aq[i][1], aq[i][2], aq[i][3]);
        }
    }
    __syncthreads();

    {
        size_t nbase = (size_t)n * CC * HWP;
        int hb = ph*KK, wb = pw*KK;
        for (int i = t; i < CC*DD; i += 512) {
            int c = i / DD, d = i - (i/DD)*DD;
            int kh = d / KK, kw2 = d - kh*KK;
            int h = hb + kh, w = wb + kw2;
            if (h < HH && w < WW) {
                int li = (c*HH + h)*WW + w;
                xe[nbase + li] = s_ex[c*PAD + d] * s_me[d] + exn[li];
                xq[nbase + li] = s_q [c*PAD + d] * s_mq[d] + qn[li];
            }
        }
    }
}

// ---------------------------------------------------------------------------
// Fused pair of depthwise 3x3 + BN + ReLU. f32 in, bf16 out (pw consumes it).
// ---------------------------------------------------------------------------
__global__ __launch_bounds__(256) void dw2_kernel(
    const float* __restrict__ xA, unsigned short* __restrict__ yA,
    const float* __restrict__ xB, unsigned short* __restrict__ yB,
    const float* __restrict__ wdw, const float* __restrict__ g,
    const float* __restrict__ b, int CoutTot, int coffA, int coffB)
{
    int bid = blockIdx.x;
    int sel = bid >> 12;
    int idx = (bid & 4095) * 256 + threadIdx.x;
    const float* x = sel ? xB : xA;
    unsigned short* y = sel ? yB : yA;
    int coff          = sel ? coffB : coffA;

    int w4 = (idx & 31) * 4;
    int h4 = ((idx >> 5) & 31) * 4;
    int nc = idx >> 10;
    int c  = nc & 127;
    int n  = nc >> 7;

    const float* wp = wdw + (coff + c) * 9;
    float wr[9];
    #pragma unroll
    for (int i = 0; i < 9; ++i) wr[i] = wp[i];

    const float* base = x + (size_t)nc * HWP;
    float acc[4][4];
    #pragma unroll
    for (int i = 0; i < 4; ++i)
        #pragma unroll
        for (int j = 0; j < 4; ++j) acc[i][j] = 0.f;

    #pragma unroll
    for (int r = 0; r < 6; ++r) {
        int hh = h4 - 1 + r;
        if (hh >= 0 && hh < HH) {
            const float* row = base + hh * WW + w4;
            float4 v = *(const float4*)row;
            float e[6];
            e[0] = (w4 > 0)   ? row[-1] : 0.f;
            e[1] = v.x; e[2] = v.y; e[3] = v.z; e[4] = v.w;
            e[5] = (w4 < 124) ? row[4]  : 0.f;
            int ilo = r - 2 > 0 ? r - 2 : 0;
            int ihi = r < 3 ? r : 3;
            for (int i = ilo; i <= ihi; ++i) {
                int j = r - i;
                float wa = wr[j*3], wb = wr[j*3+1], wc = wr[j*3+2];
                acc[i][0] += wa*e[0] + wb*e[1] + wc*e[2];
                acc[i][1] += wa*e[1] + wb*e[2] + wc*e[3];
                acc[i][2] += wa*e[2] + wb*e[3] + wc*e[4];
                acc[i][3] += wa*e[3] + wb*e[4] + wc*e[5];
            }
        }
    }
    const float rs = 0.99999500003749968f;
    float sc = g[coff + c] * rs, bi = b[coff + c];
    unsigned short* outp = y + (((size_t)n * CoutTot + coff + c) * HH + h4) * WW + w4;
    #pragma unroll
    for (int i = 0; i < 4; ++i) {
        us4 o;
        o[0] = f2bf(fmaxf(acc[i][0] * sc + bi, 0.f));
        o[1] = f2bf(fmaxf(acc[i][1] * sc + bi, 0.f));
        o[2] = f2bf(fmaxf(acc[i][2] * sc + bi, 0.f));
        o[3] = f2bf(fmaxf(acc[i][3] * sc + bi, 0.f));
        *(us4*)(outp + i * WW) = o;
    }
}

// ---------------------------------------------------------------------------
// Pointwise 1x1 (Cin -> 128) + BN + ReLU via bf16 MFMA.
// Block 256 thr = 4 waves; tile 128 o x 128 px; wave = 64x64 (4x4 16-tiles).
// K-chunks of 32 staged in LDS: W[o][k], Z^T[px][k], row stride 56 bf16
// (16B-aligned b128 frag reads, ~2-way banks). MFMA 16x16x32_bf16:
//   A[m=lane&15][k=quad*8+j], B[n=lane&15][k=quad*8+j],
//   C/D col=lane&15 (px), row=quad*4+reg (o).          [m89/m120 layouts]
// ---------------------------------------------------------------------------
#define ZSTR 56

__global__ __launch_bounds__(256, 2) void pw_mfma_kernel(
    const unsigned short* __restrict__ zA, float* __restrict__ outA,
    const unsigned short* __restrict__ zB, float* __restrict__ outB,
    const float* __restrict__ Wp, const float* __restrict__ g,
    const float* __restrict__ b, int Cin)
{
    __shared__ unsigned short s_w[128*ZSTR];   // 14.3 KB
    __shared__ unsigned short s_z[128*ZSTR];   // 14.3 KB

    const int t  = threadIdx.x;
    const int n  = blockIdx.y;
    const int p0 = blockIdx.x * 128;
    const unsigned short* z = blockIdx.z ? zB : zA;
    float* out              = blockIdx.z ? outB : outA;

    const int wave = t >> 6, lane = t & 63;
    const int wo  = (wave & 1) * 64;
    const int wp_ = (wave >> 1) * 64;
    const int lm  = lane & 15, lq = lane >> 4;

    f32x4 acc[4][4];
    #pragma unroll
    for (int i = 0; i < 4; ++i)
        #pragma unroll
        for (int j = 0; j < 4; ++j)
            #pragma unroll
            for (int r = 0; r < 4; ++r) acc[i][j][r] = 0.f;

    const unsigned short* zn = z + (size_t)n * Cin * HWP;

    for (int kb = 0; kb < Cin; kb += 32) {
        // stage W chunk (f32 -> bf16): thread t: o = t>>1, cb = (t&1)*16
        {
            int o = t >> 1, cb = (t & 1) * 16;
            const float* wrow = Wp + o * Cin + kb + cb;
            unsigned short* dst = s_w + o * ZSTR + cb;
            #pragma unroll
            for (int i = 0; i < 16; i += 4) {
                float4 v = *(const float4*)(wrow + i);
                dst[i+0] = f2bf(v.x); dst[i+1] = f2bf(v.y);
                dst[i+2] = f2bf(v.z); dst[i+3] = f2bf(v.w);
            }
        }
        // stage Z chunk transposed: thread t: cc = t&31, pxg = (t>>5)*16
        {
            int cc = t & 31, pxg = (t >> 5) * 16;
            const unsigned short* src = zn + (size_t)(kb + cc) * HWP + p0 + pxg;
            uint4 a = *(const uint4*)src;
            uint4 b2 = *(const uint4*)(src + 8);
            unsigned v[8] = {a.x, a.y, a.z, a.w, b2.x, b2.y, b2.z, b2.w};
            #pragma unroll
            for (int i = 0; i < 8; ++i) {
                s_z[(pxg + 2*i    ) * ZSTR + cc] = (unsigned short)(v[i] & 0xffffu);
                s_z[(pxg + 2*i + 1) * ZSTR + cc] = (unsigned short)(v[i] >> 16);
            }
        }
        __syncthreads();

        bf16x8 af[4], bfv[4];
        #pragma unroll
        for (int i = 0; i < 4; ++i)
            af[i] = *(const bf16x8*)&s_w[(wo + i*16 + lm) * ZSTR + lq*8];
        #pragma unroll
        for (int j = 0; j < 4; ++j)
            bfv[j] = *(const bf16x8*)&s_z[(wp_ + j*16 + lm) * ZSTR + lq*8];
        #pragma unroll
        for (int i = 0; i < 4; ++i)
            #pragma unroll
            for (int j = 0; j < 4; ++j)
                acc[i][j] = __builtin_amdgcn_mfma_f32_16x16x32_bf16(
                    af[i], bfv[j], acc[i][j], 0, 0, 0);
        __syncthreads();
    }

    const float rs = 0.99999500003749968f;
    float* on = out + (size_t)n * 128 * HWP;
    #pragma unroll
    for (int i = 0; i < 4; ++i) {
        #pragma unroll
        for (int r = 0; r < 4; ++r) {
            int o = wo + i*16 + lq*4 + r;
            float sc = g[o] * rs, bi = b[o];
            #pragma unroll
            for (int j = 0; j < 4; ++j) {
                int px = wp_ + j*16 + lm;
                on[(size_t)o * HWP + p0 + px] =
                    fmaxf(acc[i][j][r] * sc + bi, 0.f);
            }
        }
    }
}

// ---------------------------------------------------------------------------
extern "C" void kernel_launch(void* const* d_in, const int* in_sizes, int n_in,
                              void* d_out, int out_size, void* d_ws, size_t ws_size,
                              hipStream_t stream) {
    const float* exemplar = (const float*)d_in[0];
    const float* query    = (const float*)d_in[1];
    const float* w_conv_e = (const float*)d_in[2];
    const float* w_gate1  = (const float*)d_in[3];
    const float* w_gate2  = (const float*)d_in[4];
    const float* dw1_w    = (const float*)d_in[5];
    const float* bn1a_g   = (const float*)d_in[6];
    const float* bn1a_b   = (const float*)d_in[7];
    const float* pw1_w    = (const float*)d_in[8];
    const float* bn1b_g   = (const float*)d_in[9];
    const float* bn1b_b   = (const float*)d_in[10];
    const float* dwf_w    = (const float*)d_in[11];
    const float* bnfa_g   = (const float*)d_in[12];
    const float* bnfa_b   = (const float*)d_in[13];
    const float* pwf_w    = (const float*)d_in[14];
    const float* bnfb_g   = (const float*)d_in[15];
    const float* bnfb_b   = (const float*)d_in[16];

    float* out = (float*)d_out;
    float* ws  = (float*)d_ws;
    const size_t SZ = (size_t)NN * CC * HWP;
    float* bufA = ws;                                  // x_e (f32) -> y_e (f32)
    float* bufB = ws + SZ;                             // x_q (f32) -> y_q (f32)
    unsigned short* zE  = (unsigned short*)(ws + 2*SZ);        // bf16, 33.5 MB
    unsigned short* zQ  = zE + SZ;                             // bf16, 33.5 MB
    unsigned short* T16 = (unsigned short*)(ws + 3*SZ);        // bf16 (N,256,H,W)

    // 1) fused attention + gating + residual (f32)
    attn_kernel<<<dim3(PHN * PHN, NN), 512, 0, stream>>>(
        exemplar, query, w_conv_e, w_gate1, w_gate2, bufA, bufB);

    // 2) dsconv #1 depthwise: f32 -> bf16 z
    dw2_kernel<<<8192, 256, 0, stream>>>(bufA, zE, bufB, zQ,
                                         dw1_w, bn1a_g, bn1a_b, 128, 0, 0);

    // 3) dsconv #1 pointwise (MFMA): bf16 z -> f32 y
    pw_mfma_kernel<<<dim3(128, NN, 2), 256, 0, stream>>>(
        zE, bufA, zQ, bufB, pw1_w, bn1b_g, bn1b_b, 128);

    // 4) final depthwise on concat: f32 -> bf16 T (N,256,H,W)
    dw2_kernel<<<8192, 256, 0, stream>>>(bufA, T16, bufB, T16,
                                         dwf_w, bnfa_g, bnfa_b, 256, 0, 128);

    // 5) final pointwise 256 -> 128 (MFMA): bf16 T -> f32 out
    pw_mfma_kernel<<<dim3(128, NN, 1), 256, 0, stream>>>(
        T16, out, (const unsigned short*)nullptr, (float*)nullptr,
        pwf_w, bnfb_g, bnfb_b, 256);
}